// Round 4
// baseline (229.821 us; speedup 1.0000x reference)
//
#include <hip/hip_runtime.h>
#include <math.h>

#define BB 2
#define SS 2048
#define DM 1024
#define NH 16
#define HD 64

typedef __attribute__((ext_vector_type(8))) __bf16 bf16x8;
typedef __attribute__((ext_vector_type(4))) __bf16 bf16x4;
typedef __attribute__((ext_vector_type(8))) unsigned short u16x8;
typedef __attribute__((ext_vector_type(4))) float f32x4;
typedef unsigned short u16;
typedef unsigned int u32;
typedef __attribute__((address_space(1))) unsigned int u32g;
typedef __attribute__((address_space(3))) unsigned int u32l;

#define CEXP 0.18033688011112042f   // 0.125 * log2(e)

static __device__ __forceinline__ u16 f2bf(float f) {
    __bf16 h = (__bf16)f;
    return __builtin_bit_cast(unsigned short, h);
}

// async global->LDS, 16B/lane; lds base wave-uniform, lane i lands at base + i*16B
static __device__ __forceinline__ void gld16(const u16* g, u16* l) {
    __builtin_amdgcn_global_load_lds((const u32g*)g, (u32l*)l, 16, 0, 0);
}

// ---------------- fused fp32 -> bf16 cast for x + 4 weights ----------------
__global__ __launch_bounds__(256)
void cast_all(const float* __restrict__ x,
              const float* __restrict__ wq, const float* __restrict__ wk,
              const float* __restrict__ wv, const float* __restrict__ wo,
              u16* __restrict__ xb, u16* __restrict__ wqb, u16* __restrict__ wkb,
              u16* __restrict__ wvb, u16* __restrict__ wob)
{
    const int N4X = (BB * SS * DM) / 4;   // 1048576
    const int N4W = (DM * DM) / 4;        // 262144
    int i = blockIdx.x * 256 + threadIdx.x;
    const float* src; u16* dst; int off;
    if (i < N4X) { src = x; dst = xb; off = i; }
    else {
        int i2 = i - N4X;
        int w = i2 >> 18;
        off = i2 & (N4W - 1);
        switch (w) {
            case 0:  src = wq; dst = wqb; break;
            case 1:  src = wk; dst = wkb; break;
            case 2:  src = wv; dst = wvb; break;
            default: src = wo; dst = wob; break;
        }
    }
    float4 v = ((const float4*)src)[off];
    ushort4 o;
    o.x = f2bf(v.x); o.y = f2bf(v.y); o.z = f2bf(v.z); o.w = f2bf(v.w);
    ((ushort4*)dst)[off] = o;
}

// ---------------- fused QKV projection + RoPE epilogue ----------------
// 128(M) x 64(N) tile per block, X tile staged once, 3 weight tiles.
// Wave = 64 rows x 32 cols per matrix. RoPE applied to fp32 acc for Q,K.
__global__ __launch_bounds__(256, 2)
void qkv_fused(const u16* __restrict__ X,
               const u16* __restrict__ Wq, const u16* __restrict__ Wk,
               const u16* __restrict__ Wv,
               const int* __restrict__ tp, const float* __restrict__ cosp,
               const float* __restrict__ sinp, const int* __restrict__ use_rope,
               u16* __restrict__ Q, u16* __restrict__ K, u16* __restrict__ V)
{
    __shared__ u16 As[128 * 32];
    __shared__ u16 Bs[3][64 * 32];
    const int t  = threadIdx.x;
    const int wv = t >> 6, L = t & 63, ln = L & 15, qd = L >> 4;
    const int i0 = blockIdx.y * 128, j0 = blockIdx.x * 64;
    const int wm = (wv >> 1) * 64, wn = (wv & 1) * 32;
    const int srow = L >> 2, scol = (L & 3) * 8;

    f32x4 acc[3][4][2];
    #pragma unroll
    for (int w = 0; w < 3; ++w)
        #pragma unroll
        for (int mi = 0; mi < 4; ++mi)
            #pragma unroll
            for (int ni = 0; ni < 2; ++ni)
                #pragma unroll
                for (int e = 0; e < 4; ++e) acc[w][mi][ni][e] = 0.f;

    for (int k0 = 0; k0 < DM; k0 += 32) {
        __syncthreads();
        gld16(X  + (size_t)(i0 + wv * 32 +      srow) * DM + k0 + scol, &As[(wv * 32     ) * 32]);
        gld16(X  + (size_t)(i0 + wv * 32 + 16 + srow) * DM + k0 + scol, &As[(wv * 32 + 16) * 32]);
        gld16(Wq + (size_t)(j0 + wv * 16 +      srow) * DM + k0 + scol, &Bs[0][(wv * 16) * 32]);
        gld16(Wk + (size_t)(j0 + wv * 16 +      srow) * DM + k0 + scol, &Bs[1][(wv * 16) * 32]);
        gld16(Wv + (size_t)(j0 + wv * 16 +      srow) * DM + k0 + scol, &Bs[2][(wv * 16) * 32]);
        __syncthreads();
        bf16x8 a[4];
        #pragma unroll
        for (int mi = 0; mi < 4; ++mi) a[mi] = *(const bf16x8*)&As[(wm + mi * 16 + ln) * 32 + qd * 8];
        bf16x8 b[3][2];
        #pragma unroll
        for (int w = 0; w < 3; ++w)
            #pragma unroll
            for (int ni = 0; ni < 2; ++ni)
                b[w][ni] = *(const bf16x8*)&Bs[w][(wn + ni * 16 + ln) * 32 + qd * 8];
        #pragma unroll
        for (int w = 0; w < 3; ++w)
            #pragma unroll
            for (int mi = 0; mi < 4; ++mi)
                #pragma unroll
                for (int ni = 0; ni < 2; ++ni)
                    acc[w][mi][ni] = __builtin_amdgcn_mfma_f32_16x16x32_bf16(a[mi], b[w][ni], acc[w][mi][ni], 0, 0, 0);
    }

    const int rope_on = use_rope[0];
    // cos/sin per (ni): pair index p = (wn + ni*16 + ln) >> 1, shared by the lane pair
    #pragma unroll
    for (int mi = 0; mi < 4; ++mi)
        #pragma unroll
        for (int r = 0; r < 4; ++r) {
            int gi = i0 + wm + mi * 16 + qd * 4 + r;
            int b_ = gi >> 11, s = gi & 2047;
            int pos = tp[s];
            #pragma unroll
            for (int ni = 0; ni < 2; ++ni) {
                int gj = j0 + wn + ni * 16 + ln;
                int h = gj >> 6, d = gj & 63;
                size_t oidx = (((size_t)(b_ * NH + h)) * SS + s) * HD + d;
                float qv = acc[0][mi][ni][r];
                float kv = acc[1][mi][ni][r];
                float qp = __shfl_xor(qv, 1);
                float kp = __shfl_xor(kv, 1);
                if (rope_on) {
                    int p = d >> 1;
                    float c  = cosp[pos * 32 + p];
                    float sn = sinp[pos * 32 + p];
                    if (d & 1) { qv = qv * c + qp * sn; kv = kv * c + kp * sn; }
                    else       { qv = qv * c - qp * sn; kv = kv * c - kp * sn; }
                }
                Q[oidx] = f2bf(qv);
                K[oidx] = f2bf(kv);
                V[oidx] = f2bf(acc[2][mi][ni][r]);
            }
        }
}

// ---------------- output projection, 128x64 tile, fp32 out ----------------
__global__ __launch_bounds__(256, 2)
void out_gemm(const u16* __restrict__ X, const u16* __restrict__ W,
              float* __restrict__ dst)
{
    __shared__ u16 As[128 * 32];
    __shared__ u16 Bs[64 * 32];
    const int t  = threadIdx.x;
    const int wv = t >> 6, L = t & 63, ln = L & 15, qd = L >> 4;
    const int i0 = blockIdx.y * 128, j0 = blockIdx.x * 64;
    const int wm = (wv >> 1) * 64, wn = (wv & 1) * 32;
    const int srow = L >> 2, scol = (L & 3) * 8;

    f32x4 acc[4][2];
    #pragma unroll
    for (int mi = 0; mi < 4; ++mi)
        #pragma unroll
        for (int ni = 0; ni < 2; ++ni)
            #pragma unroll
            for (int e = 0; e < 4; ++e) acc[mi][ni][e] = 0.f;

    for (int k0 = 0; k0 < DM; k0 += 32) {
        __syncthreads();
        gld16(X + (size_t)(i0 + wv * 32 +      srow) * DM + k0 + scol, &As[(wv * 32     ) * 32]);
        gld16(X + (size_t)(i0 + wv * 32 + 16 + srow) * DM + k0 + scol, &As[(wv * 32 + 16) * 32]);
        gld16(W + (size_t)(j0 + wv * 16 +      srow) * DM + k0 + scol, &Bs[(wv * 16) * 32]);
        __syncthreads();
        bf16x8 a[4], b[2];
        #pragma unroll
        for (int mi = 0; mi < 4; ++mi) a[mi] = *(const bf16x8*)&As[(wm + mi * 16 + ln) * 32 + qd * 8];
        #pragma unroll
        for (int ni = 0; ni < 2; ++ni) b[ni] = *(const bf16x8*)&Bs[(wn + ni * 16 + ln) * 32 + qd * 8];
        #pragma unroll
        for (int mi = 0; mi < 4; ++mi)
            #pragma unroll
            for (int ni = 0; ni < 2; ++ni)
                acc[mi][ni] = __builtin_amdgcn_mfma_f32_16x16x32_bf16(a[mi], b[ni], acc[mi][ni], 0, 0, 0);
    }

    #pragma unroll
    for (int mi = 0; mi < 4; ++mi)
        #pragma unroll
        for (int ni = 0; ni < 2; ++ni)
            #pragma unroll
            for (int r = 0; r < 4; ++r) {
                int gi = i0 + wm + mi * 16 + qd * 4 + r;
                int gj = j0 + wn + ni * 16 + ln;
                dst[(size_t)gi * DM + gj] = acc[mi][ni][r];
            }
}

// ---------------- MFMA flash attention ----------------
// S^T trick + paired q-tiles (p, 31-p). K-frags direct from global (A-layout
// = global layout). V transposed into double-buffered LDS; ONE barrier/tile.
static __device__ __forceinline__ void group_step(
    const bf16x8 af[4][2], const bf16x8 qf[2], u16* psw,
    int diag, int rowg, int j0, int ln, int qd,
    float& m, float& l, f32x4* o, bf16x8& pf0, bf16x8& pf1)
{
    f32x4 s[4];
    #pragma unroll
    for (int mt = 0; mt < 4; ++mt) {
        #pragma unroll
        for (int e = 0; e < 4; ++e) s[mt][e] = 0.f;
        s[mt] = __builtin_amdgcn_mfma_f32_16x16x32_bf16(af[mt][0], qf[0], s[mt], 0, 0, 0);
        s[mt] = __builtin_amdgcn_mfma_f32_16x16x32_bf16(af[mt][1], qf[1], s[mt], 0, 0, 0);
    }
    if (diag) {
        #pragma unroll
        for (int mt = 0; mt < 4; ++mt)
            #pragma unroll
            for (int r = 0; r < 4; ++r)
                if (j0 + mt * 16 + qd * 4 + r > rowg) s[mt][r] = -3.0e38f;
    }
    float rm = s[0][0];
    #pragma unroll
    for (int mt = 0; mt < 4; ++mt)
        #pragma unroll
        for (int r = 0; r < 4; ++r) rm = fmaxf(rm, s[mt][r]);
    rm = fmaxf(rm, __shfl_xor(rm, 16));
    rm = fmaxf(rm, __shfl_xor(rm, 32));
    float nm = fmaxf(m, rm);
    float alpha = exp2f((m - nm) * CEXP);
    float nmc = nm * CEXP;
    float rs = 0.f;
    #pragma unroll
    for (int mt = 0; mt < 4; ++mt) {
        bf16x4 pk;
        #pragma unroll
        for (int r = 0; r < 4; ++r) {
            float pv = exp2f(fmaf(s[mt][r], CEXP, -nmc));
            rs += pv;
            pk[r] = (__bf16)pv;
        }
        *(bf16x4*)(psw + ln * 72 + mt * 16 + qd * 4) = pk;
    }
    rs += __shfl_xor(rs, 16);
    rs += __shfl_xor(rs, 32);
    l = l * alpha + rs;
    m = nm;
    #pragma unroll
    for (int r = 0; r < 4; ++r) {
        float ar = __shfl(alpha, qd * 4 + r);
        #pragma unroll
        for (int ni = 0; ni < 4; ++ni) o[ni][r] *= ar;
    }
    pf0 = *(const bf16x8*)(psw + ln * 72 + qd * 8);
    pf1 = *(const bf16x8*)(psw + ln * 72 + 32 + qd * 8);
}

__global__ __launch_bounds__(256, 2)
void attn_kernel(const u16* __restrict__ Q, const u16* __restrict__ K,
                 const u16* __restrict__ V, u16* __restrict__ Y)
{
    __shared__ u16 Vt[2][64 * 64];       // [d][key], 8-chunk XOR swizzle, double-buffered
    __shared__ u16 Ps[4][2][16 * 72];    // per-wave P round-trip

    const int t  = threadIdx.x;
    const int wv = t >> 6, L = t & 63, ln = L & 15, qd = L >> 4;
    const int bh = blockIdx.x, p = blockIdx.y;
    const int qbA = p * 64, qbB = (31 - p) * 64;
    const u16* Qp = Q + (size_t)bh * SS * HD;
    const u16* Kp = K + (size_t)bh * SS * HD;
    const u16* Vp = V + (size_t)bh * SS * HD;
    const int vkp = t & 31, vdg = t >> 5;     // V-stage: 2 keys x 8 d per thread

    bf16x8 qfA[2], qfB[2];
    {
        const u16* ra = Qp + (size_t)(qbA + wv * 16 + ln) * HD;
        qfA[0] = *(const bf16x8*)(ra + qd * 8);
        qfA[1] = *(const bf16x8*)(ra + 32 + qd * 8);
        const u16* rb = Qp + (size_t)(qbB + wv * 16 + ln) * HD;
        qfB[0] = *(const bf16x8*)(rb + qd * 8);
        qfB[1] = *(const bf16x8*)(rb + 32 + qd * 8);
    }

    f32x4 oA[4], oB[4];
    #pragma unroll
    for (int ni = 0; ni < 4; ++ni)
        #pragma unroll
        for (int e = 0; e < 4; ++e) { oA[ni][e] = 0.f; oB[ni][e] = 0.f; }
    float mA = -3.0e38f, lA = 0.f, mB = -3.0e38f, lB = 0.f;

    const int ntile = 32 - p;

    // prologue: stage V tile 0
    {
        const u16* v0 = Vp + (size_t)(2 * vkp) * HD + vdg * 8;
        u16x8 va = *(const u16x8*)v0;
        u16x8 vb = *(const u16x8*)(v0 + HD);
        #pragma unroll
        for (int u = 0; u < 8; ++u) {
            int d = vdg * 8 + u;
            u32 w = (u32)va[u] | ((u32)vb[u] << 16);
            *(u32*)&Vt[0][d * 64 + ((vkp >> 2) ^ (d & 7)) * 8 + 2 * (vkp & 3)] = w;
        }
    }
    // K fragments for tile 0 (A-operand == global K layout)
    bf16x8 af[4][2];
    #pragma unroll
    for (int mt = 0; mt < 4; ++mt)
        #pragma unroll
        for (int kc = 0; kc < 2; ++kc)
            af[mt][kc] = *(const bf16x8*)(Kp + (size_t)(mt * 16 + ln) * HD + kc * 32 + qd * 8);
    __syncthreads();

    for (int tix = 0; tix < ntile; ++tix) {
        const int j0 = tix * 64;
        const int buf = tix & 1;
        const bool more = (tix + 1 < ntile);

        // prefetch next tile's V (regs) and K (frags) — latency hidden by compute
        u16x8 nva, nvb;
        bf16x8 afn[4][2];
        if (more) {
            const u16* v0 = Vp + (size_t)(j0 + 64 + 2 * vkp) * HD + vdg * 8;
            nva = *(const u16x8*)v0;
            nvb = *(const u16x8*)(v0 + HD);
            #pragma unroll
            for (int mt = 0; mt < 4; ++mt)
                #pragma unroll
                for (int kc = 0; kc < 2; ++kc)
                    afn[mt][kc] = *(const bf16x8*)(Kp + (size_t)(j0 + 64 + mt * 16 + ln) * HD + kc * 32 + qd * 8);
        }

        const bool hasA = (tix <= p);
        bf16x8 pA0, pA1, pB0, pB1;
        if (hasA)
            group_step(af, qfA, &Ps[wv][0][0], tix == p, qbA + wv * 16 + ln, j0, ln, qd,
                       mA, lA, oA, pA0, pA1);
        group_step(af, qfB, &Ps[wv][1][0], tix == ntile - 1, qbB + wv * 16 + ln, j0, ln, qd,
                   mB, lB, oB, pB0, pB1);

        #pragma unroll
        for (int kc = 0; kc < 2; ++kc)
            #pragma unroll
            for (int ni = 0; ni < 4; ++ni) {
                bf16x8 vf = *(const bf16x8*)&Vt[buf][(ni * 16 + ln) * 64 + (((kc * 4 + qd) ^ (ln & 7)) * 8)];
                if (hasA)
                    oA[ni] = __builtin_amdgcn_mfma_f32_16x16x32_bf16(kc ? pA1 : pA0, vf, oA[ni], 0, 0, 0);
                oB[ni] = __builtin_amdgcn_mfma_f32_16x16x32_bf16(kc ? pB1 : pB0, vf, oB[ni], 0, 0, 0);
            }

        // store next V tile into the other buffer (its last readers finished
        // in iter tix-1, before the barrier at the end of iter tix-1)
        if (more) {
            #pragma unroll
            for (int u = 0; u < 8; ++u) {
                int d = vdg * 8 + u;
                u32 w = (u32)nva[u] | ((u32)nvb[u] << 16);
                *(u32*)&Vt[buf ^ 1][d * 64 + ((vkp >> 2) ^ (d & 7)) * 8 + 2 * (vkp & 3)] = w;
            }
            #pragma unroll
            for (int mt = 0; mt < 4; ++mt)
                #pragma unroll
                for (int kc = 0; kc < 2; ++kc)
                    af[mt][kc] = afn[mt][kc];
        }
        __syncthreads();
    }

    // epilogue: normalize, write Y bf16 (b, s, d_model)
    const int b = bh >> 4, h = bh & 15;
    #pragma unroll
    for (int r = 0; r < 4; ++r) {
        float invA = 1.f / __shfl(lA, qd * 4 + r);
        float invB = 1.f / __shfl(lB, qd * 4 + r);
        int sA = qbA + wv * 16 + qd * 4 + r;
        int sB = qbB + wv * 16 + qd * 4 + r;
        #pragma unroll
        for (int ni = 0; ni < 4; ++ni) {
            int d = ni * 16 + ln;
            Y[((size_t)(b * SS + sA)) * DM + h * HD + d] = f2bf(oA[ni][r] * invA);
            Y[((size_t)(b * SS + sB)) * DM + h * HD + d] = f2bf(oB[ni][r] * invB);
        }
    }
}

extern "C" void kernel_launch(void* const* d_in, const int* in_sizes, int n_in,
                              void* d_out, int out_size, void* d_ws, size_t ws_size,
                              hipStream_t stream)
{
    const float* x        = (const float*)d_in[0];
    const int*   tp       = (const int*)d_in[1];
    const int*   use_rope = (const int*)d_in[2];
    const float* Wq       = (const float*)d_in[3];
    const float* Wk       = (const float*)d_in[4];
    const float* Wv       = (const float*)d_in[5];
    const float* Wo       = (const float*)d_in[6];
    const float* cosp     = (const float*)d_in[7];
    const float* sinp     = (const float*)d_in[8];
    float* out = (float*)d_out;

    char* ws = (char*)d_ws;
    const size_t MB = 1 << 20;
    u16* xb  = (u16*)(ws);
    u16* Wqb = (u16*)(ws + 8 * MB);
    u16* Wkb = (u16*)(ws + 10 * MB);
    u16* Wvb = (u16*)(ws + 12 * MB);
    u16* Wob = (u16*)(ws + 14 * MB);
    u16* Qb  = (u16*)(ws + 16 * MB);
    u16* Kb  = (u16*)(ws + 24 * MB);
    u16* Vb  = (u16*)(ws + 32 * MB);
    u16* Yb  = (u16*)(ws + 40 * MB);

    cast_all<<<8192, 256, 0, stream>>>(x, Wq, Wk, Wv, Wo, xb, Wqb, Wkb, Wvb, Wob);
    qkv_fused<<<dim3(DM / 64, BB * SS / 128), 256, 0, stream>>>(
        xb, Wqb, Wkb, Wvb, tp, cosp, sinp, use_rope, Qb, Kb, Vb);
    attn_kernel<<<dim3(BB * NH, 16), 256, 0, stream>>>(Qb, Kb, Vb, Yb);
    out_gemm<<<dim3(DM / 64, BB * SS / 128), 256, 0, stream>>>(Yb, Wob, out);
}

// Round 5
// 201.337 us; speedup vs baseline: 1.1415x; 1.1415x over previous
//
#include <hip/hip_runtime.h>
#include <math.h>

#define BB 2
#define SS 2048
#define DM 1024
#define NH 16
#define HD 64

typedef __attribute__((ext_vector_type(8))) __bf16 bf16x8;
typedef __attribute__((ext_vector_type(4))) __bf16 bf16x4;
typedef __attribute__((ext_vector_type(8))) unsigned short u16x8;
typedef __attribute__((ext_vector_type(4))) float f32x4;
typedef unsigned short u16;
typedef unsigned int u32;
typedef __attribute__((address_space(1))) unsigned int u32g;
typedef __attribute__((address_space(3))) unsigned int u32l;

#define CEXP 0.18033688011112042f   // 0.125 * log2(e)

static __device__ __forceinline__ u16 f2bf(float f) {
    __bf16 h = (__bf16)f;
    return __builtin_bit_cast(unsigned short, h);
}

// async global->LDS, 16B/lane; lds base wave-uniform, lane i lands at base + i*16B
static __device__ __forceinline__ void gld16(const u16* g, u16* l) {
    __builtin_amdgcn_global_load_lds((const u32g*)g, (u32l*)l, 16, 0, 0);
}

// ---------------- fused fp32 -> bf16 cast for x + 4 weights ----------------
__global__ __launch_bounds__(256)
void cast_all(const float* __restrict__ x,
              const float* __restrict__ wq, const float* __restrict__ wk,
              const float* __restrict__ wv, const float* __restrict__ wo,
              u16* __restrict__ xb, u16* __restrict__ wqb, u16* __restrict__ wkb,
              u16* __restrict__ wvb, u16* __restrict__ wob)
{
    const int N4X = (BB * SS * DM) / 4;   // 1048576
    const int N4W = (DM * DM) / 4;        // 262144
    int i = blockIdx.x * 256 + threadIdx.x;
    const float* src; u16* dst; int off;
    if (i < N4X) { src = x; dst = xb; off = i; }
    else {
        int i2 = i - N4X;
        int w = i2 >> 18;
        off = i2 & (N4W - 1);
        switch (w) {
            case 0:  src = wq; dst = wqb; break;
            case 1:  src = wk; dst = wkb; break;
            case 2:  src = wv; dst = wvb; break;
            default: src = wo; dst = wob; break;
        }
    }
    float4 v = ((const float4*)src)[off];
    ushort4 o;
    o.x = f2bf(v.x); o.y = f2bf(v.y); o.z = f2bf(v.z); o.w = f2bf(v.w);
    ((ushort4*)dst)[off] = o;
}

// ---------------- QKV projection, BK=64, XOR-swizzled staging, fused RoPE ----------------
// C[i,j] = sum_k X[i,k]*W[j,k]; z selects Q/K/V. RoPE applied to fp32 acc in epilogue
// for z<2 (lane pairs hold adjacent d -> shfl_xor(.,1) pairing).
// Swizzle: LDS row r (64 u16 = 128B), chunk c_lds holds global chunk c_lds^(r&7).
__global__ __launch_bounds__(256, 2)
void qkv_gemm(const u16* __restrict__ X,
              const u16* __restrict__ Wq, const u16* __restrict__ Wk,
              const u16* __restrict__ Wv,
              const int* __restrict__ tp, const float* __restrict__ cosp,
              const float* __restrict__ sinp, const int* __restrict__ use_rope,
              u16* __restrict__ Q, u16* __restrict__ K, u16* __restrict__ V)
{
    const u16* W; u16* dst;
    if (blockIdx.z == 0)      { W = Wq; dst = Q; }
    else if (blockIdx.z == 1) { W = Wk; dst = K; }
    else                      { W = Wv; dst = V; }

    __shared__ u16 As[128 * 64];
    __shared__ u16 Bs[128 * 64];
    const int t  = threadIdx.x;
    const int wv = t >> 6, L = t & 63, ln = L & 15, qd = L >> 4;
    const int i0 = blockIdx.y * 128, j0 = blockIdx.x * 128;
    const int wm = (wv >> 1) * 64, wn = (wv & 1) * 64;
    const int srow = L >> 3;                       // 0..7 within 8-row group
    const int scg  = ((L & 7) ^ (L >> 3)) * 8;     // swizzled global chunk

    f32x4 acc[4][4];
    #pragma unroll
    for (int a = 0; a < 4; ++a)
        #pragma unroll
        for (int b = 0; b < 4; ++b)
            #pragma unroll
            for (int e = 0; e < 4; ++e) acc[a][b][e] = 0.f;

    for (int k0 = 0; k0 < DM; k0 += 64) {
        __syncthreads();
        #pragma unroll
        for (int g = 0; g < 4; ++g) {
            int rb = wv * 32 + g * 8;
            gld16(X + (size_t)(i0 + rb + srow) * DM + k0 + scg, &As[rb * 64]);
            gld16(W + (size_t)(j0 + rb + srow) * DM + k0 + scg, &Bs[rb * 64]);
        }
        __syncthreads();
        bf16x8 a[4][2], b[4][2];
        #pragma unroll
        for (int mi = 0; mi < 4; ++mi)
            #pragma unroll
            for (int kd = 0; kd < 2; ++kd)
                a[mi][kd] = *(const bf16x8*)&As[(wm + mi * 16 + ln) * 64 + (((kd * 4 + qd) ^ (ln & 7)) * 8)];
        #pragma unroll
        for (int ni = 0; ni < 4; ++ni)
            #pragma unroll
            for (int kd = 0; kd < 2; ++kd)
                b[ni][kd] = *(const bf16x8*)&Bs[(wn + ni * 16 + ln) * 64 + (((kd * 4 + qd) ^ (ln & 7)) * 8)];
        #pragma unroll
        for (int kd = 0; kd < 2; ++kd)
            #pragma unroll
            for (int mi = 0; mi < 4; ++mi)
                #pragma unroll
                for (int ni = 0; ni < 4; ++ni)
                    acc[mi][ni] = __builtin_amdgcn_mfma_f32_16x16x32_bf16(a[mi][kd], b[ni][kd], acc[mi][ni], 0, 0, 0);
    }

    const int rope_on = (blockIdx.z < 2) ? use_rope[0] : 0;
    #pragma unroll
    for (int mi = 0; mi < 4; ++mi)
        #pragma unroll
        for (int r = 0; r < 4; ++r) {
            int gi = i0 + wm + mi * 16 + qd * 4 + r;
            int b_ = gi >> 11, s = gi & 2047;
            int pos = tp[s];
            #pragma unroll
            for (int ni = 0; ni < 4; ++ni) {
                int gj = j0 + wn + ni * 16 + ln;
                int h = gj >> 6, d = gj & 63;
                float v = acc[mi][ni][r];
                float pv = __shfl_xor(v, 1);
                if (rope_on) {
                    int p = d >> 1;
                    float c  = cosp[pos * 32 + p];
                    float sn = sinp[pos * 32 + p];
                    v = (d & 1) ? (v * c + pv * sn) : (v * c - pv * sn);
                }
                dst[(((size_t)(b_ * NH + h)) * SS + s) * HD + d] = f2bf(v);
            }
        }
}

// ---------------- output projection, BK=64, swizzled, fp32 out ----------------
__global__ __launch_bounds__(256, 2)
void out_gemm(const u16* __restrict__ X, const u16* __restrict__ W,
              float* __restrict__ dst)
{
    __shared__ u16 As[128 * 64];
    __shared__ u16 Bs[128 * 64];
    const int t  = threadIdx.x;
    const int wv = t >> 6, L = t & 63, ln = L & 15, qd = L >> 4;
    const int i0 = blockIdx.y * 128, j0 = blockIdx.x * 128;
    const int wm = (wv >> 1) * 64, wn = (wv & 1) * 64;
    const int srow = L >> 3;
    const int scg  = ((L & 7) ^ (L >> 3)) * 8;

    f32x4 acc[4][4];
    #pragma unroll
    for (int a = 0; a < 4; ++a)
        #pragma unroll
        for (int b = 0; b < 4; ++b)
            #pragma unroll
            for (int e = 0; e < 4; ++e) acc[a][b][e] = 0.f;

    for (int k0 = 0; k0 < DM; k0 += 64) {
        __syncthreads();
        #pragma unroll
        for (int g = 0; g < 4; ++g) {
            int rb = wv * 32 + g * 8;
            gld16(X + (size_t)(i0 + rb + srow) * DM + k0 + scg, &As[rb * 64]);
            gld16(W + (size_t)(j0 + rb + srow) * DM + k0 + scg, &Bs[rb * 64]);
        }
        __syncthreads();
        bf16x8 a[4][2], b[4][2];
        #pragma unroll
        for (int mi = 0; mi < 4; ++mi)
            #pragma unroll
            for (int kd = 0; kd < 2; ++kd)
                a[mi][kd] = *(const bf16x8*)&As[(wm + mi * 16 + ln) * 64 + (((kd * 4 + qd) ^ (ln & 7)) * 8)];
        #pragma unroll
        for (int ni = 0; ni < 4; ++ni)
            #pragma unroll
            for (int kd = 0; kd < 2; ++kd)
                b[ni][kd] = *(const bf16x8*)&Bs[(wn + ni * 16 + ln) * 64 + (((kd * 4 + qd) ^ (ln & 7)) * 8)];
        #pragma unroll
        for (int kd = 0; kd < 2; ++kd)
            #pragma unroll
            for (int mi = 0; mi < 4; ++mi)
                #pragma unroll
                for (int ni = 0; ni < 4; ++ni)
                    acc[mi][ni] = __builtin_amdgcn_mfma_f32_16x16x32_bf16(a[mi][kd], b[ni][kd], acc[mi][ni], 0, 0, 0);
    }

    #pragma unroll
    for (int mi = 0; mi < 4; ++mi)
        #pragma unroll
        for (int ni = 0; ni < 4; ++ni)
            #pragma unroll
            for (int r = 0; r < 4; ++r) {
                int gi = i0 + wm + mi * 16 + qd * 4 + r;
                int gj = j0 + wn + ni * 16 + ln;
                dst[(size_t)gi * DM + gj] = acc[mi][ni][r];
            }
}

// ---------------- MFMA flash attention (R3 structure) ----------------
// S^T trick + paired q-tiles (p, 31-p): 33 tile-units per block, perfect balance.
static __device__ __forceinline__ void group_step(
    const bf16x8 af[4][2], const bf16x8 qf[2], u16* psw,
    int diag, int rowg, int j0, int ln, int qd,
    float& m, float& l, f32x4* o, bf16x8& pf0, bf16x8& pf1)
{
    f32x4 s[4];
    #pragma unroll
    for (int mt = 0; mt < 4; ++mt) {
        #pragma unroll
        for (int e = 0; e < 4; ++e) s[mt][e] = 0.f;
        s[mt] = __builtin_amdgcn_mfma_f32_16x16x32_bf16(af[mt][0], qf[0], s[mt], 0, 0, 0);
        s[mt] = __builtin_amdgcn_mfma_f32_16x16x32_bf16(af[mt][1], qf[1], s[mt], 0, 0, 0);
    }
    if (diag) {
        #pragma unroll
        for (int mt = 0; mt < 4; ++mt)
            #pragma unroll
            for (int r = 0; r < 4; ++r)
                if (j0 + mt * 16 + qd * 4 + r > rowg) s[mt][r] = -3.0e38f;
    }
    float rm = s[0][0];
    #pragma unroll
    for (int mt = 0; mt < 4; ++mt)
        #pragma unroll
        for (int r = 0; r < 4; ++r) rm = fmaxf(rm, s[mt][r]);
    rm = fmaxf(rm, __shfl_xor(rm, 16));
    rm = fmaxf(rm, __shfl_xor(rm, 32));
    float nm = fmaxf(m, rm);
    float alpha = exp2f((m - nm) * CEXP);
    float nmc = nm * CEXP;
    float rs = 0.f;
    #pragma unroll
    for (int mt = 0; mt < 4; ++mt) {
        bf16x4 pk;
        #pragma unroll
        for (int r = 0; r < 4; ++r) {
            float pv = exp2f(fmaf(s[mt][r], CEXP, -nmc));
            rs += pv;
            pk[r] = (__bf16)pv;
        }
        *(bf16x4*)(psw + ln * 72 + mt * 16 + qd * 4) = pk;
    }
    rs += __shfl_xor(rs, 16);
    rs += __shfl_xor(rs, 32);
    l = l * alpha + rs;
    m = nm;
    #pragma unroll
    for (int r = 0; r < 4; ++r) {
        float ar = __shfl(alpha, qd * 4 + r);
        #pragma unroll
        for (int ni = 0; ni < 4; ++ni) o[ni][r] *= ar;
    }
    pf0 = *(const bf16x8*)(psw + ln * 72 + qd * 8);
    pf1 = *(const bf16x8*)(psw + ln * 72 + 32 + qd * 8);
}

__global__ __launch_bounds__(256, 2)
void attn_kernel(const u16* __restrict__ Q, const u16* __restrict__ K,
                 const u16* __restrict__ V, u16* __restrict__ Y)
{
    __shared__ u16 Ks[64 * 64];          // [key][d], 8-chunk XOR swizzle
    __shared__ u16 Vt[64 * 64];          // [d][key], 8-chunk XOR swizzle
    __shared__ u16 Ps[4][2][16 * 72];    // per-wave P round-trip

    const int t  = threadIdx.x;
    const int wv = t >> 6, L = t & 63, ln = L & 15, qd = L >> 4;
    const int bh = blockIdx.x, p = blockIdx.y;
    const int qbA = p * 64, qbB = (31 - p) * 64;
    const u16* Qp = Q + (size_t)bh * SS * HD;
    const u16* Kp = K + (size_t)bh * SS * HD;
    const u16* Vp = V + (size_t)bh * SS * HD;

    bf16x8 qfA[2], qfB[2];
    {
        const u16* ra = Qp + (size_t)(qbA + wv * 16 + ln) * HD;
        qfA[0] = *(const bf16x8*)(ra + qd * 8);
        qfA[1] = *(const bf16x8*)(ra + 32 + qd * 8);
        const u16* rb = Qp + (size_t)(qbB + wv * 16 + ln) * HD;
        qfB[0] = *(const bf16x8*)(rb + qd * 8);
        qfB[1] = *(const bf16x8*)(rb + 32 + qd * 8);
    }

    f32x4 oA[4], oB[4];
    #pragma unroll
    for (int ni = 0; ni < 4; ++ni)
        #pragma unroll
        for (int e = 0; e < 4; ++e) { oA[ni][e] = 0.f; oB[ni][e] = 0.f; }
    float mA = -3.0e38f, lA = 0.f, mB = -3.0e38f, lB = 0.f;

    const int ntile = 32 - p;
    for (int tix = 0; tix < ntile; ++tix) {
        const int j0 = tix * 64;
        __syncthreads();
        #pragma unroll
        for (int cc = 0; cc < 2; ++cc) {
            int c = t + cc * 256;
            int kr = c >> 3, c8 = c & 7;
            u16x8 val = *(const u16x8*)(Kp + (size_t)(j0 + kr) * HD + c8 * 8);
            *(u16x8*)&Ks[kr * 64 + ((c8 ^ (kr & 7)) * 8)] = val;
        }
        {
            int kp = t & 31, dg = t >> 5;
            const u16* v0 = Vp + (size_t)(j0 + 2 * kp) * HD + dg * 8;
            u16x8 va = *(const u16x8*)v0;
            u16x8 vb = *(const u16x8*)(v0 + HD);
            #pragma unroll
            for (int u = 0; u < 8; ++u) {
                int d = dg * 8 + u;
                u32 w = (u32)va[u] | ((u32)vb[u] << 16);
                *(u32*)&Vt[d * 64 + ((kp >> 2) ^ (d & 7)) * 8 + 2 * (kp & 3)] = w;
            }
        }
        __syncthreads();

        bf16x8 af[4][2];
        #pragma unroll
        for (int mt = 0; mt < 4; ++mt)
            #pragma unroll
            for (int kc = 0; kc < 2; ++kc)
                af[mt][kc] = *(const bf16x8*)&Ks[(mt * 16 + ln) * 64 + (((kc * 4 + qd) ^ (ln & 7)) * 8)];

        const bool hasA = (tix <= p);
        bf16x8 pA0, pA1, pB0, pB1;
        if (hasA)
            group_step(af, qfA, &Ps[wv][0][0], tix == p, qbA + wv * 16 + ln, j0, ln, qd,
                       mA, lA, oA, pA0, pA1);
        group_step(af, qfB, &Ps[wv][1][0], tix == ntile - 1, qbB + wv * 16 + ln, j0, ln, qd,
                   mB, lB, oB, pB0, pB1);

        #pragma unroll
        for (int kc = 0; kc < 2; ++kc)
            #pragma unroll
            for (int ni = 0; ni < 4; ++ni) {
                bf16x8 vf = *(const bf16x8*)&Vt[(ni * 16 + ln) * 64 + (((kc * 4 + qd) ^ (ln & 7)) * 8)];
                if (hasA)
                    oA[ni] = __builtin_amdgcn_mfma_f32_16x16x32_bf16(kc ? pA1 : pA0, vf, oA[ni], 0, 0, 0);
                oB[ni] = __builtin_amdgcn_mfma_f32_16x16x32_bf16(kc ? pB1 : pB0, vf, oB[ni], 0, 0, 0);
            }
    }

    const int b = bh >> 4, h = bh & 15;
    #pragma unroll
    for (int r = 0; r < 4; ++r) {
        float invA = 1.f / __shfl(lA, qd * 4 + r);
        float invB = 1.f / __shfl(lB, qd * 4 + r);
        int sA = qbA + wv * 16 + qd * 4 + r;
        int sB = qbB + wv * 16 + qd * 4 + r;
        #pragma unroll
        for (int ni = 0; ni < 4; ++ni) {
            int d = ni * 16 + ln;
            Y[((size_t)(b * SS + sA)) * DM + h * HD + d] = f2bf(oA[ni][r] * invA);
            Y[((size_t)(b * SS + sB)) * DM + h * HD + d] = f2bf(oB[ni][r] * invB);
        }
    }
}

extern "C" void kernel_launch(void* const* d_in, const int* in_sizes, int n_in,
                              void* d_out, int out_size, void* d_ws, size_t ws_size,
                              hipStream_t stream)
{
    const float* x        = (const float*)d_in[0];
    const int*   tp       = (const int*)d_in[1];
    const int*   use_rope = (const int*)d_in[2];
    const float* Wq       = (const float*)d_in[3];
    const float* Wk       = (const float*)d_in[4];
    const float* Wv       = (const float*)d_in[5];
    const float* Wo       = (const float*)d_in[6];
    const float* cosp     = (const float*)d_in[7];
    const float* sinp     = (const float*)d_in[8];
    float* out = (float*)d_out;

    char* ws = (char*)d_ws;
    const size_t MB = 1 << 20;
    u16* xb  = (u16*)(ws);
    u16* Wqb = (u16*)(ws + 8 * MB);
    u16* Wkb = (u16*)(ws + 10 * MB);
    u16* Wvb = (u16*)(ws + 12 * MB);
    u16* Wob = (u16*)(ws + 14 * MB);
    u16* Qb  = (u16*)(ws + 16 * MB);
    u16* Kb  = (u16*)(ws + 24 * MB);
    u16* Vb  = (u16*)(ws + 32 * MB);
    u16* Yb  = (u16*)(ws + 40 * MB);

    cast_all<<<8192, 256, 0, stream>>>(x, Wq, Wk, Wv, Wo, xb, Wqb, Wkb, Wvb, Wob);
    qkv_gemm<<<dim3(DM / 128, BB * SS / 128, 3), 256, 0, stream>>>(
        xb, Wqb, Wkb, Wvb, tp, cosp, sinp, use_rope, Qb, Kb, Vb);
    attn_kernel<<<dim3(BB * NH, 16), 256, 0, stream>>>(Qb, Kb, Vb, Yb);
    out_gemm<<<dim3(DM / 128, BB * SS / 128), 256, 0, stream>>>(Yb, Wob, out);
}

// Round 6
// 196.422 us; speedup vs baseline: 1.1700x; 1.0250x over previous
//
#include <hip/hip_runtime.h>
#include <math.h>

#define BB 2
#define SS 2048
#define DM 1024
#define NH 16
#define HD 64

typedef __attribute__((ext_vector_type(8))) __bf16 bf16x8;
typedef __attribute__((ext_vector_type(4))) __bf16 bf16x4;
typedef __attribute__((ext_vector_type(8))) unsigned short u16x8;
typedef __attribute__((ext_vector_type(4))) float f32x4;
typedef unsigned short u16;
typedef unsigned int u32;
typedef __attribute__((address_space(1))) unsigned int u32g;
typedef __attribute__((address_space(3))) unsigned int u32l;

#define CEXP 0.18033688011112042f   // 0.125 * log2(e)

static __device__ __forceinline__ u16 f2bf(float f) {
    __bf16 h = (__bf16)f;
    return __builtin_bit_cast(unsigned short, h);
}
static __device__ __forceinline__ float bfu2f(u16 v) {
    return __uint_as_float(((u32)v) << 16);
}

// async global->LDS, 16B/lane; lds base wave-uniform, lane i lands at base + i*16B
static __device__ __forceinline__ void gld16(const u16* g, u16* l) {
    __builtin_amdgcn_global_load_lds((const u32g*)g, (u32l*)l, 16, 0, 0);
}

// ---------------- fused fp32 -> bf16 cast for x + 4 weights ----------------
__global__ __launch_bounds__(256)
void cast_all(const float* __restrict__ x,
              const float* __restrict__ wq, const float* __restrict__ wk,
              const float* __restrict__ wv, const float* __restrict__ wo,
              u16* __restrict__ xb, u16* __restrict__ wqb, u16* __restrict__ wkb,
              u16* __restrict__ wvb, u16* __restrict__ wob)
{
    const int N4X = (BB * SS * DM) / 4;   // 1048576
    const int N4W = (DM * DM) / 4;        // 262144
    int i = blockIdx.x * 256 + threadIdx.x;
    const float* src; u16* dst; int off;
    if (i < N4X) { src = x; dst = xb; off = i; }
    else {
        int i2 = i - N4X;
        int w = i2 >> 18;
        off = i2 & (N4W - 1);
        switch (w) {
            case 0:  src = wq; dst = wqb; break;
            case 1:  src = wk; dst = wkb; break;
            case 2:  src = wv; dst = wvb; break;
            default: src = wo; dst = wob; break;
        }
    }
    float4 v = ((const float4*)src)[off];
    ushort4 o;
    o.x = f2bf(v.x); o.y = f2bf(v.y); o.z = f2bf(v.z); o.w = f2bf(v.w);
    ((ushort4*)dst)[off] = o;
}

// ---------------- QKV projection, BK=64 swizzled gld16, LDS-transposed epilogue + RoPE --------
__global__ __launch_bounds__(256, 3)
void qkv_gemm(const u16* __restrict__ X,
              const u16* __restrict__ Wq, const u16* __restrict__ Wk,
              const u16* __restrict__ Wv,
              const int* __restrict__ tp, const float* __restrict__ cosp,
              const float* __restrict__ sinp, const int* __restrict__ use_rope,
              u16* __restrict__ Q, u16* __restrict__ K, u16* __restrict__ V)
{
    const u16* W; u16* dst;
    if (blockIdx.z == 0)      { W = Wq; dst = Q; }
    else if (blockIdx.z == 1) { W = Wk; dst = K; }
    else                      { W = Wv; dst = V; }

    __shared__ u16 SH[4 * 64 * 68];   // 34816 B: aliases {As,Bs} during k-loop, Ts after
    u16* As = SH;                     // 128 x 64
    u16* Bs = SH + 8192;              // 128 x 64
    const int t  = threadIdx.x;
    const int wv = t >> 6, L = t & 63, ln = L & 15, qd = L >> 4;
    const int i0 = blockIdx.y * 128, j0 = blockIdx.x * 128;
    const int wm = (wv >> 1) * 64, wn = (wv & 1) * 64;
    const int srow = L >> 3;
    const int scg  = ((L & 7) ^ (L >> 3)) * 8;

    f32x4 acc[4][4];
    #pragma unroll
    for (int a = 0; a < 4; ++a)
        #pragma unroll
        for (int b = 0; b < 4; ++b)
            #pragma unroll
            for (int e = 0; e < 4; ++e) acc[a][b][e] = 0.f;

    for (int k0 = 0; k0 < DM; k0 += 64) {
        __syncthreads();
        #pragma unroll
        for (int g = 0; g < 4; ++g) {
            int rb = wv * 32 + g * 8;
            gld16(X + (size_t)(i0 + rb + srow) * DM + k0 + scg, &As[rb * 64]);
            gld16(W + (size_t)(j0 + rb + srow) * DM + k0 + scg, &Bs[rb * 64]);
        }
        __syncthreads();
        bf16x8 a[4][2], b[4][2];
        #pragma unroll
        for (int mi = 0; mi < 4; ++mi)
            #pragma unroll
            for (int kd = 0; kd < 2; ++kd)
                a[mi][kd] = *(const bf16x8*)&As[(wm + mi * 16 + ln) * 64 + (((kd * 4 + qd) ^ (ln & 7)) * 8)];
        #pragma unroll
        for (int ni = 0; ni < 4; ++ni)
            #pragma unroll
            for (int kd = 0; kd < 2; ++kd)
                b[ni][kd] = *(const bf16x8*)&Bs[(wn + ni * 16 + ln) * 64 + (((kd * 4 + qd) ^ (ln & 7)) * 8)];
        #pragma unroll
        for (int kd = 0; kd < 2; ++kd)
            #pragma unroll
            for (int mi = 0; mi < 4; ++mi)
                #pragma unroll
                for (int ni = 0; ni < 4; ++ni)
                    acc[mi][ni] = __builtin_amdgcn_mfma_f32_16x16x32_bf16(a[mi][kd], b[ni][kd], acc[mi][ni], 0, 0, 0);
    }

    // ---- epilogue: per-wave LDS transpose -> coalesced u16x8 stores, in-lane RoPE ----
    __syncthreads();
    u16* Ts = SH + wv * (64 * 68);    // 64 rows (s) x 64 cols (d), stride 68
    #pragma unroll
    for (int mi = 0; mi < 4; ++mi)
        #pragma unroll
        for (int ni = 0; ni < 4; ++ni)
            #pragma unroll
            for (int r = 0; r < 4; ++r)
                Ts[(mi * 16 + qd * 4 + r) * 68 + ni * 16 + ln] = f2bf(acc[mi][ni][r]);

    const int rope_on = (blockIdx.z < 2) ? use_rope[0] : 0;
    const int h  = blockIdx.x * 2 + (wv & 1);
    const int sb = i0 + wm;
    const int lrow = L >> 3, lcol = (L & 7) * 8;
    #pragma unroll
    for (int r2 = 0; r2 < 8; ++r2) {
        int row = lrow + r2 * 8;
        u16x8 val = *(const u16x8*)&Ts[row * 68 + lcol];
        int sg = sb + row;
        int b_ = sg >> 11, s = sg & 2047;
        if (rope_on) {
            int pos = tp[s];
            float cc[4], sc[4];
            *(float4*)cc = *(const float4*)&cosp[pos * 32 + (lcol >> 1)];
            *(float4*)sc = *(const float4*)&sinp[pos * 32 + (lcol >> 1)];
            #pragma unroll
            for (int j = 0; j < 4; ++j) {
                float e = bfu2f(val[2 * j]), o = bfu2f(val[2 * j + 1]);
                val[2 * j]     = f2bf(e * cc[j] - o * sc[j]);
                val[2 * j + 1] = f2bf(o * cc[j] + e * sc[j]);
            }
        }
        *(u16x8*)&dst[(((size_t)(b_ * NH + h)) * SS + s) * HD + lcol] = val;
    }
}

// ---------------- output projection, 128x64 tile, fp32 transposed epilogue ----------------
__global__ __launch_bounds__(256, 2)
void out_gemm(const u16* __restrict__ X, const u16* __restrict__ W,
              float* __restrict__ dst)
{
    __shared__ char SHB[36864];       // {As 16K, Bs 8K} k-loop; Ts 36K epilogue
    u16* As = (u16*)SHB;              // 128 x 64
    u16* Bs = (u16*)SHB + 8192;       // 64 x 64
    const int t  = threadIdx.x;
    const int wv = t >> 6, L = t & 63, ln = L & 15, qd = L >> 4;
    const int i0 = blockIdx.y * 128, j0 = blockIdx.x * 64;
    const int wm = (wv >> 1) * 64, wn = (wv & 1) * 32;
    const int srow = L >> 3;
    const int scg  = ((L & 7) ^ (L >> 3)) * 8;

    f32x4 acc[4][2];
    #pragma unroll
    for (int mi = 0; mi < 4; ++mi)
        #pragma unroll
        for (int ni = 0; ni < 2; ++ni)
            #pragma unroll
            for (int e = 0; e < 4; ++e) acc[mi][ni][e] = 0.f;

    for (int k0 = 0; k0 < DM; k0 += 64) {
        __syncthreads();
        #pragma unroll
        for (int g = 0; g < 4; ++g) {
            int rb = wv * 32 + g * 8;
            gld16(X + (size_t)(i0 + rb + srow) * DM + k0 + scg, &As[rb * 64]);
        }
        #pragma unroll
        for (int g = 0; g < 2; ++g) {
            int rb = wv * 16 + g * 8;
            gld16(W + (size_t)(j0 + rb + srow) * DM + k0 + scg, &Bs[rb * 64]);
        }
        __syncthreads();
        bf16x8 a[4][2], b[2][2];
        #pragma unroll
        for (int mi = 0; mi < 4; ++mi)
            #pragma unroll
            for (int kd = 0; kd < 2; ++kd)
                a[mi][kd] = *(const bf16x8*)&As[(wm + mi * 16 + ln) * 64 + (((kd * 4 + qd) ^ (ln & 7)) * 8)];
        #pragma unroll
        for (int ni = 0; ni < 2; ++ni)
            #pragma unroll
            for (int kd = 0; kd < 2; ++kd)
                b[ni][kd] = *(const bf16x8*)&Bs[(wn + ni * 16 + ln) * 64 + (((kd * 4 + qd) ^ (ln & 7)) * 8)];
        #pragma unroll
        for (int kd = 0; kd < 2; ++kd)
            #pragma unroll
            for (int mi = 0; mi < 4; ++mi)
                #pragma unroll
                for (int ni = 0; ni < 2; ++ni)
                    acc[mi][ni] = __builtin_amdgcn_mfma_f32_16x16x32_bf16(a[mi][kd], b[ni][kd], acc[mi][ni], 0, 0, 0);
    }

    // ---- epilogue: per-wave fp32 LDS transpose -> dense float4 stores ----
    __syncthreads();
    float* Ts = (float*)SHB + wv * (64 * 36);   // 64 rows x 32 cols, stride 36
    #pragma unroll
    for (int mi = 0; mi < 4; ++mi)
        #pragma unroll
        for (int ni = 0; ni < 2; ++ni)
            #pragma unroll
            for (int r = 0; r < 4; ++r)
                Ts[(mi * 16 + qd * 4 + r) * 36 + ni * 16 + ln] = acc[mi][ni][r];

    const int lrow = L >> 3, lch = L & 7;
    #pragma unroll
    for (int r2 = 0; r2 < 8; ++r2) {
        int row = lrow + r2 * 8;
        float4 v = *(const float4*)&Ts[row * 36 + lch * 4];
        *(float4*)&dst[(size_t)(i0 + wm + row) * DM + j0 + wn + lch * 4] = v;
    }
}

// ---------------- MFMA flash attention, 128-key chunks, paired q-tiles ----------------
static __device__ __forceinline__ void step128(
    const u16* KsB, const bf16x8 qf[2], u16* psw,
    bool mask, int rowg, int j0, int ln, int qd,
    float& m, float& l, f32x4* o, bf16x8 pf[4])
{
    f32x4 s[8];
    #pragma unroll
    for (int mt = 0; mt < 8; ++mt) {
        bf16x8 a0 = *(const bf16x8*)&KsB[(mt * 16 + ln) * 64 + ((qd ^ (ln & 7)) * 8)];
        bf16x8 a1 = *(const bf16x8*)&KsB[(mt * 16 + ln) * 64 + (((4 + qd) ^ (ln & 7)) * 8)];
        #pragma unroll
        for (int e = 0; e < 4; ++e) s[mt][e] = 0.f;
        s[mt] = __builtin_amdgcn_mfma_f32_16x16x32_bf16(a0, qf[0], s[mt], 0, 0, 0);
        s[mt] = __builtin_amdgcn_mfma_f32_16x16x32_bf16(a1, qf[1], s[mt], 0, 0, 0);
    }
    if (mask) {
        #pragma unroll
        for (int mt = 0; mt < 8; ++mt)
            #pragma unroll
            for (int r = 0; r < 4; ++r)
                if (j0 + mt * 16 + qd * 4 + r > rowg) s[mt][r] = -3.0e38f;
    }
    float rm = s[0][0];
    #pragma unroll
    for (int mt = 0; mt < 8; ++mt)
        #pragma unroll
        for (int r = 0; r < 4; ++r) rm = fmaxf(rm, s[mt][r]);
    rm = fmaxf(rm, __shfl_xor(rm, 16));
    rm = fmaxf(rm, __shfl_xor(rm, 32));
    float nm = fmaxf(m, rm);
    float alpha = exp2f((m - nm) * CEXP);
    float nmc = nm * CEXP;
    float rs = 0.f;
    #pragma unroll
    for (int mt = 0; mt < 8; ++mt) {
        bf16x4 pk;
        #pragma unroll
        for (int r = 0; r < 4; ++r) {
            float pv = exp2f(fmaf(s[mt][r], CEXP, -nmc));
            rs += pv;
            pk[r] = (__bf16)pv;
        }
        *(bf16x4*)(psw + ln * 136 + mt * 16 + qd * 4) = pk;
    }
    rs += __shfl_xor(rs, 16);
    rs += __shfl_xor(rs, 32);
    l = l * alpha + rs;
    m = nm;
    #pragma unroll
    for (int r = 0; r < 4; ++r) {
        float ar = __shfl(alpha, qd * 4 + r);
        #pragma unroll
        for (int ni = 0; ni < 4; ++ni) o[ni][r] *= ar;
    }
    #pragma unroll
    for (int kc = 0; kc < 4; ++kc)
        pf[kc] = *(const bf16x8*)(psw + ln * 136 + kc * 32 + qd * 8);
}

__global__ __launch_bounds__(256, 2)
void attn_kernel(const u16* __restrict__ Q, const u16* __restrict__ K,
                 const u16* __restrict__ V, u16* __restrict__ Y)
{
    __shared__ u16 Ks[128 * 64];       // [key][d], source-swizzled via gld16
    __shared__ u16 Vt[64 * 128];       // [d][key], 16-chunk XOR swizzle
    __shared__ u16 Ps[4][16 * 136];    // per-wave P round-trip (A/B share sequentially)

    const int t  = threadIdx.x;
    const int wv = t >> 6, L = t & 63, ln = L & 15, qd = L >> 4;
    const int bh = blockIdx.x, p = blockIdx.y;
    const int qbA = p * 64, qbB = (31 - p) * 64;
    const int cA = (p >> 1) + 1;
    const int ntile = (33 - p) >> 1;
    const u16* Qp = Q + (size_t)bh * SS * HD;
    const u16* Kp = K + (size_t)bh * SS * HD;
    const u16* Vp = V + (size_t)bh * SS * HD;
    const int srow = L >> 3;
    const int scg  = ((L & 7) ^ (L >> 3)) * 8;
    const int vkp = t & 63;            // key-pair
    const int vdg0 = t >> 6;           // d-group base

    bf16x8 qfA[2], qfB[2];
    {
        const u16* ra = Qp + (size_t)(qbA + wv * 16 + ln) * HD;
        qfA[0] = *(const bf16x8*)(ra + qd * 8);
        qfA[1] = *(const bf16x8*)(ra + 32 + qd * 8);
        const u16* rb = Qp + (size_t)(qbB + wv * 16 + ln) * HD;
        qfB[0] = *(const bf16x8*)(rb + qd * 8);
        qfB[1] = *(const bf16x8*)(rb + 32 + qd * 8);
    }

    f32x4 oA[4], oB[4];
    #pragma unroll
    for (int ni = 0; ni < 4; ++ni)
        #pragma unroll
        for (int e = 0; e < 4; ++e) { oA[ni][e] = 0.f; oB[ni][e] = 0.f; }
    float mA = -3.0e38f, lA = 0.f, mB = -3.0e38f, lB = 0.f;

    for (int tix = 0; tix < ntile; ++tix) {
        const int j0 = tix * 128;
        __syncthreads();
        // ---- stage K (async, swizzle folded into the global chunk choice) ----
        #pragma unroll
        for (int g = 0; g < 4; ++g) {
            int rb = wv * 32 + g * 8;
            gld16(Kp + (size_t)(j0 + rb + srow) * HD + scg, &Ks[rb * 64]);
        }
        // ---- stage V transposed (2 passes: 64 pairs x 8 d-groups) ----
        #pragma unroll
        for (int vvp = 0; vvp < 2; ++vvp) {
            int dg = vdg0 + 4 * vvp;
            const u16* v0 = Vp + (size_t)(j0 + 2 * vkp) * HD + dg * 8;
            u16x8 va = *(const u16x8*)v0;
            u16x8 vb = *(const u16x8*)(v0 + HD);
            #pragma unroll
            for (int u = 0; u < 8; ++u) {
                int d = dg * 8 + u;
                u32 w = (u32)va[u] | ((u32)vb[u] << 16);
                *(u32*)&Vt[d * 128 + (((vkp >> 2) ^ (d & 7)) * 8) + 2 * (vkp & 3)] = w;
            }
        }
        __syncthreads();

        const bool hasA = (tix < cA);
        bf16x8 pA[4], pB[4];
        if (hasA)
            step128(Ks, qfA, &Ps[wv][0], tix == cA - 1, qbA + wv * 16 + ln, j0, ln, qd,
                    mA, lA, oA, pA);
        step128(Ks, qfB, &Ps[wv][0], tix == ntile - 1, qbB + wv * 16 + ln, j0, ln, qd,
                mB, lB, oB, pB);

        // ---- O += P.V (Vt fragments shared by both groups) ----
        #pragma unroll
        for (int kc = 0; kc < 4; ++kc)
            #pragma unroll
            for (int ni = 0; ni < 4; ++ni) {
                bf16x8 vf = *(const bf16x8*)&Vt[(ni * 16 + ln) * 128 + (((kc * 4 + qd) ^ (ln & 7)) * 8)];
                if (hasA)
                    oA[ni] = __builtin_amdgcn_mfma_f32_16x16x32_bf16(pA[kc], vf, oA[ni], 0, 0, 0);
                oB[ni] = __builtin_amdgcn_mfma_f32_16x16x32_bf16(pB[kc], vf, oB[ni], 0, 0, 0);
            }
    }

    // ---- epilogue: normalize, write Y bf16 (b, s, d_model) ----
    const int b = bh >> 4, h = bh & 15;
    #pragma unroll
    for (int r = 0; r < 4; ++r) {
        float invA = 1.f / __shfl(lA, qd * 4 + r);
        float invB = 1.f / __shfl(lB, qd * 4 + r);
        int sA = qbA + wv * 16 + qd * 4 + r;
        int sB = qbB + wv * 16 + qd * 4 + r;
        #pragma unroll
        for (int ni = 0; ni < 4; ++ni) {
            int d = ni * 16 + ln;
            Y[((size_t)(b * SS + sA)) * DM + h * HD + d] = f2bf(oA[ni][r] * invA);
            Y[((size_t)(b * SS + sB)) * DM + h * HD + d] = f2bf(oB[ni][r] * invB);
        }
    }
}

extern "C" void kernel_launch(void* const* d_in, const int* in_sizes, int n_in,
                              void* d_out, int out_size, void* d_ws, size_t ws_size,
                              hipStream_t stream)
{
    const float* x        = (const float*)d_in[0];
    const int*   tp       = (const int*)d_in[1];
    const int*   use_rope = (const int*)d_in[2];
    const float* Wq       = (const float*)d_in[3];
    const float* Wk       = (const float*)d_in[4];
    const float* Wv       = (const float*)d_in[5];
    const float* Wo       = (const float*)d_in[6];
    const float* cosp     = (const float*)d_in[7];
    const float* sinp     = (const float*)d_in[8];
    float* out = (float*)d_out;

    char* ws = (char*)d_ws;
    const size_t MB = 1 << 20;
    u16* xb  = (u16*)(ws);
    u16* Wqb = (u16*)(ws + 8 * MB);
    u16* Wkb = (u16*)(ws + 10 * MB);
    u16* Wvb = (u16*)(ws + 12 * MB);
    u16* Wob = (u16*)(ws + 14 * MB);
    u16* Qb  = (u16*)(ws + 16 * MB);
    u16* Kb  = (u16*)(ws + 24 * MB);
    u16* Vb  = (u16*)(ws + 32 * MB);
    u16* Yb  = (u16*)(ws + 40 * MB);

    cast_all<<<8192, 256, 0, stream>>>(x, Wq, Wk, Wv, Wo, xb, Wqb, Wkb, Wvb, Wob);
    qkv_gemm<<<dim3(DM / 128, BB * SS / 128, 3), 256, 0, stream>>>(
        xb, Wqb, Wkb, Wvb, tp, cosp, sinp, use_rope, Qb, Kb, Vb);
    attn_kernel<<<dim3(BB * NH, 16), 256, 0, stream>>>(Qb, Kb, Vb, Yb);
    out_gemm<<<dim3(DM / 64, BB * SS / 128), 256, 0, stream>>>(Yb, Wob, out);
}

// Round 7
// 193.440 us; speedup vs baseline: 1.1881x; 1.0154x over previous
//
#include <hip/hip_runtime.h>
#include <math.h>

#define BB 2
#define SS 2048
#define DM 1024
#define NH 16
#define HD 64

typedef __attribute__((ext_vector_type(8))) __bf16 bf16x8;
typedef __attribute__((ext_vector_type(4))) __bf16 bf16x4;
typedef __attribute__((ext_vector_type(8))) unsigned short u16x8;
typedef __attribute__((ext_vector_type(4))) float f32x4;
typedef unsigned short u16;
typedef unsigned int u32;
typedef __attribute__((address_space(1))) unsigned int u32g;
typedef __attribute__((address_space(3))) unsigned int u32l;

#define CEXP 0.18033688011112042f   // 0.125 * log2(e)

static __device__ __forceinline__ u16 f2bf(float f) {
    __bf16 h = (__bf16)f;
    return __builtin_bit_cast(unsigned short, h);
}

// async global->LDS, 16B/lane; lds base wave-uniform, lane i lands at base + i*16B
static __device__ __forceinline__ void gld16(const u16* g, u16* l) {
    __builtin_amdgcn_global_load_lds((const u32g*)g, (u32l*)l, 16, 0, 0);
}

// ---------------- fused fp32 -> bf16 cast for x + 4 weights ----------------
__global__ __launch_bounds__(256)
void cast_all(const float* __restrict__ x,
              const float* __restrict__ wq, const float* __restrict__ wk,
              const float* __restrict__ wv, const float* __restrict__ wo,
              u16* __restrict__ xb, u16* __restrict__ wqb, u16* __restrict__ wkb,
              u16* __restrict__ wvb, u16* __restrict__ wob)
{
    const int N4X = (BB * SS * DM) / 4;   // 1048576
    const int N4W = (DM * DM) / 4;        // 262144
    int i = blockIdx.x * 256 + threadIdx.x;
    const float* src; u16* dst; int off;
    if (i < N4X) { src = x; dst = xb; off = i; }
    else {
        int i2 = i - N4X;
        int w = i2 >> 18;
        off = i2 & (N4W - 1);
        switch (w) {
            case 0:  src = wq; dst = wqb; break;
            case 1:  src = wk; dst = wkb; break;
            case 2:  src = wv; dst = wvb; break;
            default: src = wo; dst = wob; break;
        }
    }
    float4 v = ((const float4*)src)[off];
    ushort4 o;
    o.x = f2bf(v.x); o.y = f2bf(v.y); o.z = f2bf(v.z); o.w = f2bf(v.w);
    ((ushort4*)dst)[off] = o;
}

// ---------------- QKV projection: BK=64 swizzled gld16; fp32 RoPE; transposed epilogue ------
__global__ __launch_bounds__(256, 3)
void qkv_gemm(const u16* __restrict__ X,
              const u16* __restrict__ Wq, const u16* __restrict__ Wk,
              const u16* __restrict__ Wv,
              const int* __restrict__ tp, const float* __restrict__ cosp,
              const float* __restrict__ sinp, const int* __restrict__ use_rope,
              u16* __restrict__ Q, u16* __restrict__ K, u16* __restrict__ V)
{
    const u16* W; u16* dst;
    if (blockIdx.z == 0)      { W = Wq; dst = Q; }
    else if (blockIdx.z == 1) { W = Wk; dst = K; }
    else                      { W = Wv; dst = V; }

    __shared__ u16 SH[4 * 64 * 68];   // 34816 B: {As,Bs} during k-loop; Ts after
    u16* As = SH;                     // 128 x 64
    u16* Bs = SH + 8192;              // 128 x 64
    const int t  = threadIdx.x;
    const int wv = t >> 6, L = t & 63, ln = L & 15, qd = L >> 4;
    const int i0 = blockIdx.y * 128, j0 = blockIdx.x * 128;
    const int wm = (wv >> 1) * 64, wn = (wv & 1) * 64;
    const int srow = L >> 3;
    const int scg  = ((L & 7) ^ (L >> 3)) * 8;

    f32x4 acc[4][4];
    #pragma unroll
    for (int a = 0; a < 4; ++a)
        #pragma unroll
        for (int b = 0; b < 4; ++b)
            #pragma unroll
            for (int e = 0; e < 4; ++e) acc[a][b][e] = 0.f;

    for (int k0 = 0; k0 < DM; k0 += 64) {
        __syncthreads();
        #pragma unroll
        for (int g = 0; g < 4; ++g) {
            int rb = wv * 32 + g * 8;
            gld16(X + (size_t)(i0 + rb + srow) * DM + k0 + scg, &As[rb * 64]);
            gld16(W + (size_t)(j0 + rb + srow) * DM + k0 + scg, &Bs[rb * 64]);
        }
        __syncthreads();
        bf16x8 a[4][2], b[4][2];
        #pragma unroll
        for (int mi = 0; mi < 4; ++mi)
            #pragma unroll
            for (int kd = 0; kd < 2; ++kd)
                a[mi][kd] = *(const bf16x8*)&As[(wm + mi * 16 + ln) * 64 + (((kd * 4 + qd) ^ (ln & 7)) * 8)];
        #pragma unroll
        for (int ni = 0; ni < 4; ++ni)
            #pragma unroll
            for (int kd = 0; kd < 2; ++kd)
                b[ni][kd] = *(const bf16x8*)&Bs[(wn + ni * 16 + ln) * 64 + (((kd * 4 + qd) ^ (ln & 7)) * 8)];
        #pragma unroll
        for (int kd = 0; kd < 2; ++kd)
            #pragma unroll
            for (int mi = 0; mi < 4; ++mi)
                #pragma unroll
                for (int ni = 0; ni < 4; ++ni)
                    acc[mi][ni] = __builtin_amdgcn_mfma_f32_16x16x32_bf16(a[mi][kd], b[ni][kd], acc[mi][ni], 0, 0, 0);
    }

    // ---- RoPE in fp32 on accumulators (lane pairs hold adjacent d) ----
    const int rope_on = (blockIdx.z < 2) ? use_rope[0] : 0;
    if (rope_on) {
        #pragma unroll
        for (int mi = 0; mi < 4; ++mi)
            #pragma unroll
            for (int r = 0; r < 4; ++r) {
                int gi = i0 + wm + mi * 16 + qd * 4 + r;
                int s = gi & 2047;
                int pos = tp[s];
                #pragma unroll
                for (int ni = 0; ni < 4; ++ni) {
                    int d = wn + ni * 16 + ln;   // head-dim index (mod 64 via h split below)
                    int dh = d & 63;
                    float c  = cosp[pos * 32 + (dh >> 1)];
                    float sn = sinp[pos * 32 + (dh >> 1)];
                    float v = acc[mi][ni][r];
                    float pv = __shfl_xor(v, 1);
                    acc[mi][ni][r] = (dh & 1) ? (v * c + pv * sn) : (v * c - pv * sn);
                }
            }
    }

    // ---- epilogue: per-wave LDS transpose -> coalesced u16x8 stores ----
    __syncthreads();
    u16* Ts = SH + wv * (64 * 68);    // 64 rows (s) x 64 cols (d), stride 68
    #pragma unroll
    for (int mi = 0; mi < 4; ++mi)
        #pragma unroll
        for (int ni = 0; ni < 4; ++ni)
            #pragma unroll
            for (int r = 0; r < 4; ++r)
                Ts[(mi * 16 + qd * 4 + r) * 68 + ni * 16 + ln] = f2bf(acc[mi][ni][r]);

    const int h  = blockIdx.x * 2 + (wv & 1);
    const int sb = i0 + wm;
    const int lrow = L >> 3, lcol = (L & 7) * 8;
    #pragma unroll
    for (int r2 = 0; r2 < 8; ++r2) {
        int row = lrow + r2 * 8;
        u16x8 val = *(const u16x8*)&Ts[row * 68 + lcol];
        int sg = sb + row;
        int b_ = sg >> 11, s = sg & 2047;
        *(u16x8*)&dst[(((size_t)(b_ * NH + h)) * SS + s) * HD + lcol] = val;
    }
}

// ---------------- output projection, 128x64 tile, fp32 transposed epilogue ----------------
__global__ __launch_bounds__(256, 2)
void out_gemm(const u16* __restrict__ X, const u16* __restrict__ W,
              float* __restrict__ dst)
{
    __shared__ char SHB[36864];       // {As 16K, Bs 8K} k-loop; Ts 36K epilogue
    u16* As = (u16*)SHB;              // 128 x 64
    u16* Bs = (u16*)SHB + 8192;       // 64 x 64
    const int t  = threadIdx.x;
    const int wv = t >> 6, L = t & 63, ln = L & 15, qd = L >> 4;
    const int i0 = blockIdx.y * 128, j0 = blockIdx.x * 64;
    const int wm = (wv >> 1) * 64, wn = (wv & 1) * 32;
    const int srow = L >> 3;
    const int scg  = ((L & 7) ^ (L >> 3)) * 8;

    f32x4 acc[4][2];
    #pragma unroll
    for (int mi = 0; mi < 4; ++mi)
        #pragma unroll
        for (int ni = 0; ni < 2; ++ni)
            #pragma unroll
            for (int e = 0; e < 4; ++e) acc[mi][ni][e] = 0.f;

    for (int k0 = 0; k0 < DM; k0 += 64) {
        __syncthreads();
        #pragma unroll
        for (int g = 0; g < 4; ++g) {
            int rb = wv * 32 + g * 8;
            gld16(X + (size_t)(i0 + rb + srow) * DM + k0 + scg, &As[rb * 64]);
        }
        #pragma unroll
        for (int g = 0; g < 2; ++g) {
            int rb = wv * 16 + g * 8;
            gld16(W + (size_t)(j0 + rb + srow) * DM + k0 + scg, &Bs[rb * 64]);
        }
        __syncthreads();
        bf16x8 a[4][2], b[2][2];
        #pragma unroll
        for (int mi = 0; mi < 4; ++mi)
            #pragma unroll
            for (int kd = 0; kd < 2; ++kd)
                a[mi][kd] = *(const bf16x8*)&As[(wm + mi * 16 + ln) * 64 + (((kd * 4 + qd) ^ (ln & 7)) * 8)];
        #pragma unroll
        for (int ni = 0; ni < 2; ++ni)
            #pragma unroll
            for (int kd = 0; kd < 2; ++kd)
                b[ni][kd] = *(const bf16x8*)&Bs[(wn + ni * 16 + ln) * 64 + (((kd * 4 + qd) ^ (ln & 7)) * 8)];
        #pragma unroll
        for (int kd = 0; kd < 2; ++kd)
            #pragma unroll
            for (int mi = 0; mi < 4; ++mi)
                #pragma unroll
                for (int ni = 0; ni < 2; ++ni)
                    acc[mi][ni] = __builtin_amdgcn_mfma_f32_16x16x32_bf16(a[mi][kd], b[ni][kd], acc[mi][ni], 0, 0, 0);
    }

    __syncthreads();
    float* Ts = (float*)SHB + wv * (64 * 36);   // 64 rows x 32 cols, stride 36
    #pragma unroll
    for (int mi = 0; mi < 4; ++mi)
        #pragma unroll
        for (int ni = 0; ni < 2; ++ni)
            #pragma unroll
            for (int r = 0; r < 4; ++r)
                Ts[(mi * 16 + qd * 4 + r) * 36 + ni * 16 + ln] = acc[mi][ni][r];

    const int lrow = L >> 3, lch = L & 7;
    #pragma unroll
    for (int r2 = 0; r2 < 8; ++r2) {
        int row = lrow + r2 * 8;
        float4 v = *(const float4*)&Ts[row * 36 + lch * 4];
        *(float4*)&dst[(size_t)(i0 + wm + row) * DM + j0 + wn + lch * 4] = v;
    }
}

// ---------------- MFMA flash attention: 64-key tiles, dbuf K/V, one barrier/iter ----------
static __device__ __forceinline__ void group_step(
    const u16* KsB, const bf16x8 qf[2], u16* psw,
    bool diag, int rowg, int j0, int ln, int qd,
    float& m, float& l, f32x4* o, bf16x8& pf0, bf16x8& pf1)
{
    f32x4 s[4];
    #pragma unroll
    for (int mt = 0; mt < 4; ++mt) {
        bf16x8 a0 = *(const bf16x8*)&KsB[(mt * 16 + ln) * 64 + ((qd ^ (ln & 7)) * 8)];
        bf16x8 a1 = *(const bf16x8*)&KsB[(mt * 16 + ln) * 64 + (((4 + qd) ^ (ln & 7)) * 8)];
        #pragma unroll
        for (int e = 0; e < 4; ++e) s[mt][e] = 0.f;
        s[mt] = __builtin_amdgcn_mfma_f32_16x16x32_bf16(a0, qf[0], s[mt], 0, 0, 0);
        s[mt] = __builtin_amdgcn_mfma_f32_16x16x32_bf16(a1, qf[1], s[mt], 0, 0, 0);
    }
    if (diag) {
        #pragma unroll
        for (int mt = 0; mt < 4; ++mt)
            #pragma unroll
            for (int r = 0; r < 4; ++r)
                if (j0 + mt * 16 + qd * 4 + r > rowg) s[mt][r] = -3.0e38f;
    }
    float rm = s[0][0];
    #pragma unroll
    for (int mt = 0; mt < 4; ++mt)
        #pragma unroll
        for (int r = 0; r < 4; ++r) rm = fmaxf(rm, s[mt][r]);
    rm = fmaxf(rm, __shfl_xor(rm, 16));
    rm = fmaxf(rm, __shfl_xor(rm, 32));
    float nm = fmaxf(m, rm);
    float alpha = exp2f((m - nm) * CEXP);
    float nmc = nm * CEXP;
    float rs = 0.f;
    #pragma unroll
    for (int mt = 0; mt < 4; ++mt) {
        bf16x4 pk;
        #pragma unroll
        for (int r = 0; r < 4; ++r) {
            float pv = exp2f(fmaf(s[mt][r], CEXP, -nmc));
            rs += pv;
            pk[r] = (__bf16)pv;
        }
        *(bf16x4*)(psw + ln * 72 + mt * 16 + qd * 4) = pk;
    }
    rs += __shfl_xor(rs, 16);
    rs += __shfl_xor(rs, 32);
    l = l * alpha + rs;
    m = nm;
    #pragma unroll
    for (int r = 0; r < 4; ++r) {
        float ar = __shfl(alpha, qd * 4 + r);
        #pragma unroll
        for (int ni = 0; ni < 4; ++ni) o[ni][r] *= ar;
    }
    pf0 = *(const bf16x8*)(psw + ln * 72 + qd * 8);
    pf1 = *(const bf16x8*)(psw + ln * 72 + 32 + qd * 8);
}

__global__ __launch_bounds__(256, 2)
void attn_kernel(const u16* __restrict__ Q, const u16* __restrict__ K,
                 const u16* __restrict__ V, u16* __restrict__ Y)
{
    __shared__ u16 Ks[2][64 * 64];     // [key][d], gld16 source-swizzled, double-buffered
    __shared__ u16 Vt[2][64 * 64];     // [d][key], XOR swizzle, double-buffered
    __shared__ u16 Ps[4][16 * 72];     // per-wave P round-trip (A/B sequential)

    const int t  = threadIdx.x;
    const int wv = t >> 6, L = t & 63, ln = L & 15, qd = L >> 4;
    const int bh = blockIdx.x, p = blockIdx.y;
    const int qbA = p * 64, qbB = (31 - p) * 64;
    const u16* Qp = Q + (size_t)bh * SS * HD;
    const u16* Kp = K + (size_t)bh * SS * HD;
    const u16* Vp = V + (size_t)bh * SS * HD;
    const int srow = L >> 3;
    const int scg  = ((L & 7) ^ (L >> 3)) * 8;
    const int vkp = t & 31, vdg = t >> 5;    // V-stage: 2 keys x 8 d per thread

    bf16x8 qfA[2], qfB[2];
    {
        const u16* ra = Qp + (size_t)(qbA + wv * 16 + ln) * HD;
        qfA[0] = *(const bf16x8*)(ra + qd * 8);
        qfA[1] = *(const bf16x8*)(ra + 32 + qd * 8);
        const u16* rb = Qp + (size_t)(qbB + wv * 16 + ln) * HD;
        qfB[0] = *(const bf16x8*)(rb + qd * 8);
        qfB[1] = *(const bf16x8*)(rb + 32 + qd * 8);
    }

    f32x4 oA[4], oB[4];
    #pragma unroll
    for (int ni = 0; ni < 4; ++ni)
        #pragma unroll
        for (int e = 0; e < 4; ++e) { oA[ni][e] = 0.f; oB[ni][e] = 0.f; }
    float mA = -3.0e38f, lA = 0.f, mB = -3.0e38f, lB = 0.f;

    const int ntile = 32 - p;

    // ---- prologue: stage tile 0 ----
    gld16(Kp + (size_t)(wv * 16 +     srow) * HD + scg, &Ks[0][(wv * 16    ) * 64]);
    gld16(Kp + (size_t)(wv * 16 + 8 + srow) * HD + scg, &Ks[0][(wv * 16 + 8) * 64]);
    {
        const u16* v0 = Vp + (size_t)(2 * vkp) * HD + vdg * 8;
        u16x8 va = *(const u16x8*)v0;
        u16x8 vb = *(const u16x8*)(v0 + HD);
        #pragma unroll
        for (int u = 0; u < 8; ++u) {
            int d = vdg * 8 + u;
            u32 w = (u32)va[u] | ((u32)vb[u] << 16);
            *(u32*)&Vt[0][d * 64 + ((vkp >> 2) ^ (d & 7)) * 8 + 2 * (vkp & 3)] = w;
        }
    }
    __syncthreads();

    for (int tix = 0; tix < ntile; ++tix) {
        const int j0 = tix * 64;
        const int buf = tix & 1;
        const bool more = (tix + 1 < ntile);

        // ---- prefetch tile t+1: K via async gld16, V into regs ----
        u16x8 nva, nvb;
        if (more) {
            const int j1 = j0 + 64;
            gld16(Kp + (size_t)(j1 + wv * 16 +     srow) * HD + scg, &Ks[buf ^ 1][(wv * 16    ) * 64]);
            gld16(Kp + (size_t)(j1 + wv * 16 + 8 + srow) * HD + scg, &Ks[buf ^ 1][(wv * 16 + 8) * 64]);
            const u16* v1 = Vp + (size_t)(j1 + 2 * vkp) * HD + vdg * 8;
            nva = *(const u16x8*)v1;
            nvb = *(const u16x8*)(v1 + HD);
        }

        const bool hasA = (tix <= p);
        bf16x8 pA0, pA1, pB0, pB1;
        if (hasA)
            group_step(Ks[buf], qfA, &Ps[wv][0], tix == p, qbA + wv * 16 + ln, j0, ln, qd,
                       mA, lA, oA, pA0, pA1);
        group_step(Ks[buf], qfB, &Ps[wv][0], tix == ntile - 1, qbB + wv * 16 + ln, j0, ln, qd,
                   mB, lB, oB, pB0, pB1);

        #pragma unroll
        for (int kc = 0; kc < 2; ++kc)
            #pragma unroll
            for (int ni = 0; ni < 4; ++ni) {
                bf16x8 vf = *(const bf16x8*)&Vt[buf][(ni * 16 + ln) * 64 + (((kc * 4 + qd) ^ (ln & 7)) * 8)];
                if (hasA)
                    oA[ni] = __builtin_amdgcn_mfma_f32_16x16x32_bf16(kc ? pA1 : pA0, vf, oA[ni], 0, 0, 0);
                oB[ni] = __builtin_amdgcn_mfma_f32_16x16x32_bf16(kc ? pB1 : pB0, vf, oB[ni], 0, 0, 0);
            }

        // ---- write prefetched V into the other buffer ----
        if (more) {
            #pragma unroll
            for (int u = 0; u < 8; ++u) {
                int d = vdg * 8 + u;
                u32 w = (u32)nva[u] | ((u32)nvb[u] << 16);
                *(u32*)&Vt[buf ^ 1][d * 64 + ((vkp >> 2) ^ (d & 7)) * 8 + 2 * (vkp & 3)] = w;
            }
        }
        __syncthreads();
    }

    // ---- epilogue: normalize, write Y bf16 (b, s, d_model) ----
    const int b = bh >> 4, h = bh & 15;
    #pragma unroll
    for (int r = 0; r < 4; ++r) {
        float invA = 1.f / __shfl(lA, qd * 4 + r);
        float invB = 1.f / __shfl(lB, qd * 4 + r);
        int sA = qbA + wv * 16 + qd * 4 + r;
        int sB = qbB + wv * 16 + qd * 4 + r;
        #pragma unroll
        for (int ni = 0; ni < 4; ++ni) {
            int d = ni * 16 + ln;
            Y[((size_t)(b * SS + sA)) * DM + h * HD + d] = f2bf(oA[ni][r] * invA);
            Y[((size_t)(b * SS + sB)) * DM + h * HD + d] = f2bf(oB[ni][r] * invB);
        }
    }
}

extern "C" void kernel_launch(void* const* d_in, const int* in_sizes, int n_in,
                              void* d_out, int out_size, void* d_ws, size_t ws_size,
                              hipStream_t stream)
{
    const float* x        = (const float*)d_in[0];
    const int*   tp       = (const int*)d_in[1];
    const int*   use_rope = (const int*)d_in[2];
    const float* Wq       = (const float*)d_in[3];
    const float* Wk       = (const float*)d_in[4];
    const float* Wv       = (const float*)d_in[5];
    const float* Wo       = (const float*)d_in[6];
    const float* cosp     = (const float*)d_in[7];
    const float* sinp     = (const float*)d_in[8];
    float* out = (float*)d_out;

    char* ws = (char*)d_ws;
    const size_t MB = 1 << 20;
    u16* xb  = (u16*)(ws);
    u16* Wqb = (u16*)(ws + 8 * MB);
    u16* Wkb = (u16*)(ws + 10 * MB);
    u16* Wvb = (u16*)(ws + 12 * MB);
    u16* Wob = (u16*)(ws + 14 * MB);
    u16* Qb  = (u16*)(ws + 16 * MB);
    u16* Kb  = (u16*)(ws + 24 * MB);
    u16* Vb  = (u16*)(ws + 32 * MB);
    u16* Yb  = (u16*)(ws + 40 * MB);

    cast_all<<<8192, 256, 0, stream>>>(x, Wq, Wk, Wv, Wo, xb, Wqb, Wkb, Wvb, Wob);
    qkv_gemm<<<dim3(DM / 128, BB * SS / 128, 3), 256, 0, stream>>>(
        xb, Wqb, Wkb, Wvb, tp, cosp, sinp, use_rope, Qb, Kb, Vb);
    attn_kernel<<<dim3(BB * NH, 16), 256, 0, stream>>>(Qb, Kb, Vb, Yb);
    out_gemm<<<dim3(DM / 64, BB * SS / 128), 256, 0, stream>>>(Yb, Wob, out);
}

// Round 8
// 187.216 us; speedup vs baseline: 1.2276x; 1.0332x over previous
//
#include <hip/hip_runtime.h>
#include <math.h>

#define BB 2
#define SS 2048
#define DM 1024
#define NH 16
#define HD 64

typedef __attribute__((ext_vector_type(8))) __bf16 bf16x8;
typedef __attribute__((ext_vector_type(4))) __bf16 bf16x4;
typedef __attribute__((ext_vector_type(8))) unsigned short u16x8;
typedef __attribute__((ext_vector_type(4))) float f32x4;
typedef unsigned short u16;
typedef unsigned int u32;
typedef __attribute__((address_space(1))) unsigned int u32g;
typedef __attribute__((address_space(3))) unsigned int u32l;

#define CEXP 0.18033688011112042f   // 0.125 * log2(e)

static __device__ __forceinline__ u16 f2bf(float f) {
    __bf16 h = (__bf16)f;
    return __builtin_bit_cast(unsigned short, h);
}

// async global->LDS, 16B/lane; lds base wave-uniform, lane i lands at base + i*16B
static __device__ __forceinline__ void gld16(const u16* g, u16* l) {
    __builtin_amdgcn_global_load_lds((const u32g*)g, (u32l*)l, 16, 0, 0);
}

// ---------------- fused fp32 -> bf16 cast for x + 4 weights ----------------
__global__ __launch_bounds__(256)
void cast_all(const float* __restrict__ x,
              const float* __restrict__ wq, const float* __restrict__ wk,
              const float* __restrict__ wv, const float* __restrict__ wo,
              u16* __restrict__ xb, u16* __restrict__ wqb, u16* __restrict__ wkb,
              u16* __restrict__ wvb, u16* __restrict__ wob)
{
    const int N4X = (BB * SS * DM) / 4;   // 1048576
    const int N4W = (DM * DM) / 4;        // 262144
    int i = blockIdx.x * 256 + threadIdx.x;
    const float* src; u16* dst; int off;
    if (i < N4X) { src = x; dst = xb; off = i; }
    else {
        int i2 = i - N4X;
        int w = i2 >> 18;
        off = i2 & (N4W - 1);
        switch (w) {
            case 0:  src = wq; dst = wqb; break;
            case 1:  src = wk; dst = wkb; break;
            case 2:  src = wv; dst = wvb; break;
            default: src = wo; dst = wob; break;
        }
    }
    float4 v = ((const float4*)src)[off];
    ushort4 o;
    o.x = f2bf(v.x); o.y = f2bf(v.y); o.z = f2bf(v.z); o.w = f2bf(v.w);
    ((ushort4*)dst)[off] = o;
}

// ---------------- QKV projection: BK=64 swizzled gld16; fp32 RoPE; transposed epilogue ------
__global__ __launch_bounds__(256, 3)
void qkv_gemm(const u16* __restrict__ X,
              const u16* __restrict__ Wq, const u16* __restrict__ Wk,
              const u16* __restrict__ Wv,
              const int* __restrict__ tp, const float* __restrict__ cosp,
              const float* __restrict__ sinp, const int* __restrict__ use_rope,
              u16* __restrict__ Q, u16* __restrict__ K, u16* __restrict__ V)
{
    const u16* W; u16* dst;
    if (blockIdx.z == 0)      { W = Wq; dst = Q; }
    else if (blockIdx.z == 1) { W = Wk; dst = K; }
    else                      { W = Wv; dst = V; }

    __shared__ u16 SH[4 * 64 * 68];   // 34816 B: {As,Bs} during k-loop; Ts after
    u16* As = SH;                     // 128 x 64
    u16* Bs = SH + 8192;              // 128 x 64
    const int t  = threadIdx.x;
    const int wv = t >> 6, L = t & 63, ln = L & 15, qd = L >> 4;
    const int i0 = blockIdx.y * 128, j0 = blockIdx.x * 128;
    const int wm = (wv >> 1) * 64, wn = (wv & 1) * 64;
    const int srow = L >> 3;
    const int scg  = ((L & 7) ^ (L >> 3)) * 8;

    f32x4 acc[4][4];
    #pragma unroll
    for (int a = 0; a < 4; ++a)
        #pragma unroll
        for (int b = 0; b < 4; ++b)
            #pragma unroll
            for (int e = 0; e < 4; ++e) acc[a][b][e] = 0.f;

    for (int k0 = 0; k0 < DM; k0 += 64) {
        __syncthreads();
        #pragma unroll
        for (int g = 0; g < 4; ++g) {
            int rb = wv * 32 + g * 8;
            gld16(X + (size_t)(i0 + rb + srow) * DM + k0 + scg, &As[rb * 64]);
            gld16(W + (size_t)(j0 + rb + srow) * DM + k0 + scg, &Bs[rb * 64]);
        }
        __syncthreads();
        bf16x8 a[4][2], b[4][2];
        #pragma unroll
        for (int mi = 0; mi < 4; ++mi)
            #pragma unroll
            for (int kd = 0; kd < 2; ++kd)
                a[mi][kd] = *(const bf16x8*)&As[(wm + mi * 16 + ln) * 64 + (((kd * 4 + qd) ^ (ln & 7)) * 8)];
        #pragma unroll
        for (int ni = 0; ni < 4; ++ni)
            #pragma unroll
            for (int kd = 0; kd < 2; ++kd)
                b[ni][kd] = *(const bf16x8*)&Bs[(wn + ni * 16 + ln) * 64 + (((kd * 4 + qd) ^ (ln & 7)) * 8)];
        #pragma unroll
        for (int kd = 0; kd < 2; ++kd)
            #pragma unroll
            for (int mi = 0; mi < 4; ++mi)
                #pragma unroll
                for (int ni = 0; ni < 4; ++ni)
                    acc[mi][ni] = __builtin_amdgcn_mfma_f32_16x16x32_bf16(a[mi][kd], b[ni][kd], acc[mi][ni], 0, 0, 0);
    }

    // ---- RoPE in fp32 on accumulators (lane pairs hold adjacent d) ----
    const int rope_on = (blockIdx.z < 2) ? use_rope[0] : 0;
    if (rope_on) {
        #pragma unroll
        for (int mi = 0; mi < 4; ++mi)
            #pragma unroll
            for (int r = 0; r < 4; ++r) {
                int gi = i0 + wm + mi * 16 + qd * 4 + r;
                int s = gi & 2047;
                int pos = tp[s];
                #pragma unroll
                for (int ni = 0; ni < 4; ++ni) {
                    int d = wn + ni * 16 + ln;
                    int dh = d & 63;
                    float c  = cosp[pos * 32 + (dh >> 1)];
                    float sn = sinp[pos * 32 + (dh >> 1)];
                    float v = acc[mi][ni][r];
                    float pv = __shfl_xor(v, 1);
                    acc[mi][ni][r] = (dh & 1) ? (v * c + pv * sn) : (v * c - pv * sn);
                }
            }
    }

    // ---- epilogue: per-wave LDS transpose -> coalesced u16x8 stores ----
    __syncthreads();
    u16* Ts = SH + wv * (64 * 68);    // 64 rows (s) x 64 cols (d), stride 68
    #pragma unroll
    for (int mi = 0; mi < 4; ++mi)
        #pragma unroll
        for (int ni = 0; ni < 4; ++ni)
            #pragma unroll
            for (int r = 0; r < 4; ++r)
                Ts[(mi * 16 + qd * 4 + r) * 68 + ni * 16 + ln] = f2bf(acc[mi][ni][r]);

    const int h  = blockIdx.x * 2 + (wv & 1);
    const int sb = i0 + wm;
    const int lrow = L >> 3, lcol = (L & 7) * 8;
    #pragma unroll
    for (int r2 = 0; r2 < 8; ++r2) {
        int row = lrow + r2 * 8;
        u16x8 val = *(const u16x8*)&Ts[row * 68 + lcol];
        int sg = sb + row;
        int b_ = sg >> 11, s = sg & 2047;
        *(u16x8*)&dst[(((size_t)(b_ * NH + h)) * SS + s) * HD + lcol] = val;
    }
}

// ---------------- output projection, 128x64 tile, fp32 transposed epilogue ----------------
__global__ __launch_bounds__(256, 2)
void out_gemm(const u16* __restrict__ X, const u16* __restrict__ W,
              float* __restrict__ dst)
{
    __shared__ char SHB[36864];       // {As 16K, Bs 8K} k-loop; Ts 36K epilogue
    u16* As = (u16*)SHB;              // 128 x 64
    u16* Bs = (u16*)SHB + 8192;       // 64 x 64
    const int t  = threadIdx.x;
    const int wv = t >> 6, L = t & 63, ln = L & 15, qd = L >> 4;
    const int i0 = blockIdx.y * 128, j0 = blockIdx.x * 64;
    const int wm = (wv >> 1) * 64, wn = (wv & 1) * 32;
    const int srow = L >> 3;
    const int scg  = ((L & 7) ^ (L >> 3)) * 8;

    f32x4 acc[4][2];
    #pragma unroll
    for (int mi = 0; mi < 4; ++mi)
        #pragma unroll
        for (int ni = 0; ni < 2; ++ni)
            #pragma unroll
            for (int e = 0; e < 4; ++e) acc[mi][ni][e] = 0.f;

    for (int k0 = 0; k0 < DM; k0 += 64) {
        __syncthreads();
        #pragma unroll
        for (int g = 0; g < 4; ++g) {
            int rb = wv * 32 + g * 8;
            gld16(X + (size_t)(i0 + rb + srow) * DM + k0 + scg, &As[rb * 64]);
        }
        #pragma unroll
        for (int g = 0; g < 2; ++g) {
            int rb = wv * 16 + g * 8;
            gld16(W + (size_t)(j0 + rb + srow) * DM + k0 + scg, &Bs[rb * 64]);
        }
        __syncthreads();
        bf16x8 a[4][2], b[2][2];
        #pragma unroll
        for (int mi = 0; mi < 4; ++mi)
            #pragma unroll
            for (int kd = 0; kd < 2; ++kd)
                a[mi][kd] = *(const bf16x8*)&As[(wm + mi * 16 + ln) * 64 + (((kd * 4 + qd) ^ (ln & 7)) * 8)];
        #pragma unroll
        for (int ni = 0; ni < 2; ++ni)
            #pragma unroll
            for (int kd = 0; kd < 2; ++kd)
                b[ni][kd] = *(const bf16x8*)&Bs[(wn + ni * 16 + ln) * 64 + (((kd * 4 + qd) ^ (ln & 7)) * 8)];
        #pragma unroll
        for (int kd = 0; kd < 2; ++kd)
            #pragma unroll
            for (int mi = 0; mi < 4; ++mi)
                #pragma unroll
                for (int ni = 0; ni < 2; ++ni)
                    acc[mi][ni] = __builtin_amdgcn_mfma_f32_16x16x32_bf16(a[mi][kd], b[ni][kd], acc[mi][ni], 0, 0, 0);
    }

    __syncthreads();
    float* Ts = (float*)SHB + wv * (64 * 36);   // 64 rows x 32 cols, stride 36
    #pragma unroll
    for (int mi = 0; mi < 4; ++mi)
        #pragma unroll
        for (int ni = 0; ni < 2; ++ni)
            #pragma unroll
            for (int r = 0; r < 4; ++r)
                Ts[(mi * 16 + qd * 4 + r) * 36 + ni * 16 + ln] = acc[mi][ni][r];

    const int lrow = L >> 3, lch = L & 7;
    #pragma unroll
    for (int r2 = 0; r2 < 8; ++r2) {
        int row = lrow + r2 * 8;
        float4 v = *(const float4*)&Ts[row * 36 + lch * 4];
        *(float4*)&dst[(size_t)(i0 + wm + row) * DM + j0 + wn + lch * 4] = v;
    }
}

// ---------------- MFMA flash attention: 8-wave blocks, wave-group A/B specialization --------
// Waves 0-3 = q-tile p (+ V staging), waves 4-7 = q-tile 31-p. One group_step per wave
// per iter (halved critical path). Ps XOR-granule swizzle: bank-conflict-free round-trip.
static __device__ __forceinline__ void group_step(
    const u16* KsB, const bf16x8 qf[2], u16* psw,
    bool diag, int rowg, int j0, int ln, int qd,
    float& m, float& l, f32x4* o, bf16x8& pf0, bf16x8& pf1)
{
    const int pm = 2 * (ln & 7);     // even XOR mask over 8B granules
    f32x4 s[4];
    #pragma unroll
    for (int mt = 0; mt < 4; ++mt) {
        bf16x8 a0 = *(const bf16x8*)&KsB[(mt * 16 + ln) * 64 + ((qd ^ (ln & 7)) * 8)];
        bf16x8 a1 = *(const bf16x8*)&KsB[(mt * 16 + ln) * 64 + (((4 + qd) ^ (ln & 7)) * 8)];
        #pragma unroll
        for (int e = 0; e < 4; ++e) s[mt][e] = 0.f;
        s[mt] = __builtin_amdgcn_mfma_f32_16x16x32_bf16(a0, qf[0], s[mt], 0, 0, 0);
        s[mt] = __builtin_amdgcn_mfma_f32_16x16x32_bf16(a1, qf[1], s[mt], 0, 0, 0);
    }
    if (diag) {
        #pragma unroll
        for (int mt = 0; mt < 4; ++mt)
            #pragma unroll
            for (int r = 0; r < 4; ++r)
                if (j0 + mt * 16 + qd * 4 + r > rowg) s[mt][r] = -3.0e38f;
    }
    float rm = s[0][0];
    #pragma unroll
    for (int mt = 0; mt < 4; ++mt)
        #pragma unroll
        for (int r = 0; r < 4; ++r) rm = fmaxf(rm, s[mt][r]);
    rm = fmaxf(rm, __shfl_xor(rm, 16));
    rm = fmaxf(rm, __shfl_xor(rm, 32));
    float nm = fmaxf(m, rm);
    float alpha = exp2f((m - nm) * CEXP);
    float nmc = nm * CEXP;
    float rs = 0.f;
    #pragma unroll
    for (int mt = 0; mt < 4; ++mt) {
        bf16x4 pk;
        #pragma unroll
        for (int r = 0; r < 4; ++r) {
            float pv = exp2f(fmaf(s[mt][r], CEXP, -nmc));
            rs += pv;
            pk[r] = (__bf16)pv;
        }
        *(bf16x4*)(psw + ln * 64 + ((mt * 4 + qd) ^ pm) * 4) = pk;
    }
    rs += __shfl_xor(rs, 16);
    rs += __shfl_xor(rs, 32);
    l = l * alpha + rs;
    m = nm;
    #pragma unroll
    for (int r = 0; r < 4; ++r) {
        float ar = __shfl(alpha, qd * 4 + r);
        #pragma unroll
        for (int ni = 0; ni < 4; ++ni) o[ni][r] *= ar;
    }
    pf0 = *(const bf16x8*)(psw + ln * 64 + ((qd * 2) ^ pm) * 4);
    pf1 = *(const bf16x8*)(psw + ln * 64 + ((8 + qd * 2) ^ pm) * 4);
}

__global__ __launch_bounds__(512, 4)
void attn_kernel(const u16* __restrict__ Q, const u16* __restrict__ K,
                 const u16* __restrict__ V, u16* __restrict__ Y)
{
    __shared__ u16 Ks[2][64 * 64];     // [key][d], gld16 source-swizzled, double-buffered
    __shared__ u16 Vt[2][64 * 64];     // [d][key], XOR swizzle, double-buffered
    __shared__ u16 Ps[8][16 * 64];     // per-wave P round-trip, granule-swizzled

    const int t  = threadIdx.x;
    const int wv = t >> 6, L = t & 63, ln = L & 15, qd = L >> 4;
    const int wsub = wv & 3, grp = wv >> 2;
    const int bh = blockIdx.x, p = blockIdx.y;
    const int qb = (grp ? (31 - p) : p) * 64;
    const u16* Qp = Q + (size_t)bh * SS * HD;
    const u16* Kp = K + (size_t)bh * SS * HD;
    const u16* Vp = V + (size_t)bh * SS * HD;
    const int srow = L >> 3;
    const int scg  = ((L & 7) ^ (L >> 3)) * 8;
    const int vkp = t & 31, vdg = (t >> 5) & 7;   // V-stage (waves 0-3): 2 keys x 8 d

    const int ntile   = 32 - p;
    const int myTiles = grp ? ntile : (p + 1);

    bf16x8 qf[2];
    {
        const u16* rq = Qp + (size_t)(qb + wsub * 16 + ln) * HD;
        qf[0] = *(const bf16x8*)(rq + qd * 8);
        qf[1] = *(const bf16x8*)(rq + 32 + qd * 8);
    }

    f32x4 o[4];
    #pragma unroll
    for (int ni = 0; ni < 4; ++ni)
        #pragma unroll
        for (int e = 0; e < 4; ++e) o[ni][e] = 0.f;
    float m = -3.0e38f, l = 0.f;

    // ---- prologue: stage tile 0 (K: 8 waves x 8 rows; V: waves 0-3) ----
    gld16(Kp + (size_t)(wv * 8 + srow) * HD + scg, &Ks[0][(wv * 8) * 64]);
    if (t < 256) {
        const u16* v0 = Vp + (size_t)(2 * vkp) * HD + vdg * 8;
        u16x8 va = *(const u16x8*)v0;
        u16x8 vb = *(const u16x8*)(v0 + HD);
        #pragma unroll
        for (int u = 0; u < 8; ++u) {
            int d = vdg * 8 + u;
            u32 w = (u32)va[u] | ((u32)vb[u] << 16);
            *(u32*)&Vt[0][d * 64 + ((vkp >> 2) ^ (d & 7)) * 8 + 2 * (vkp & 3)] = w;
        }
    }
    __syncthreads();

    for (int tix = 0; tix < ntile; ++tix) {
        const int j0 = tix * 64;
        const int buf = tix & 1;
        const bool more = (tix + 1 < ntile);

        // ---- prefetch tile t+1: K async into buf^1, V into regs (waves 0-3) ----
        u16x8 nva = {}, nvb = {};
        if (more) {
            const int j1 = j0 + 64;
            gld16(Kp + (size_t)(j1 + wv * 8 + srow) * HD + scg, &Ks[buf ^ 1][(wv * 8) * 64]);
            if (t < 256) {
                const u16* v1 = Vp + (size_t)(j1 + 2 * vkp) * HD + vdg * 8;
                nva = *(const u16x8*)v1;
                nvb = *(const u16x8*)(v1 + HD);
            }
        }

        if (tix < myTiles) {
            bf16x8 pf0, pf1;
            group_step(Ks[buf], qf, &Ps[wv][0], tix == myTiles - 1,
                       qb + wsub * 16 + ln, j0, ln, qd, m, l, o, pf0, pf1);
            #pragma unroll
            for (int kc = 0; kc < 2; ++kc)
                #pragma unroll
                for (int ni = 0; ni < 4; ++ni) {
                    bf16x8 vf = *(const bf16x8*)&Vt[buf][(ni * 16 + ln) * 64 + (((kc * 4 + qd) ^ (ln & 7)) * 8)];
                    o[ni] = __builtin_amdgcn_mfma_f32_16x16x32_bf16(kc ? pf1 : pf0, vf, o[ni], 0, 0, 0);
                }
        }

        // ---- write prefetched V into the other buffer ----
        if (more && t < 256) {
            #pragma unroll
            for (int u = 0; u < 8; ++u) {
                int d = vdg * 8 + u;
                u32 w = (u32)nva[u] | ((u32)nvb[u] << 16);
                *(u32*)&Vt[buf ^ 1][d * 64 + ((vkp >> 2) ^ (d & 7)) * 8 + 2 * (vkp & 3)] = w;
            }
        }
        __syncthreads();
    }

    // ---- epilogue: normalize, write Y bf16 (b, s, d_model) ----
    const int b = bh >> 4, h = bh & 15;
    #pragma unroll
    for (int r = 0; r < 4; ++r) {
        float inv = 1.f / __shfl(l, qd * 4 + r);
        int sg = qb + wsub * 16 + qd * 4 + r;
        #pragma unroll
        for (int ni = 0; ni < 4; ++ni) {
            int d = ni * 16 + ln;
            Y[((size_t)(b * SS + sg)) * DM + h * HD + d] = f2bf(o[ni][r] * inv);
        }
    }
}

extern "C" void kernel_launch(void* const* d_in, const int* in_sizes, int n_in,
                              void* d_out, int out_size, void* d_ws, size_t ws_size,
                              hipStream_t stream)
{
    const float* x        = (const float*)d_in[0];
    const int*   tp       = (const int*)d_in[1];
    const int*   use_rope = (const int*)d_in[2];
    const float* Wq       = (const float*)d_in[3];
    const float* Wk       = (const float*)d_in[4];
    const float* Wv       = (const float*)d_in[5];
    const float* Wo       = (const float*)d_in[6];
    const float* cosp     = (const float*)d_in[7];
    const float* sinp     = (const float*)d_in[8];
    float* out = (float*)d_out;

    char* ws = (char*)d_ws;
    const size_t MB = 1 << 20;
    u16* xb  = (u16*)(ws);
    u16* Wqb = (u16*)(ws + 8 * MB);
    u16* Wkb = (u16*)(ws + 10 * MB);
    u16* Wvb = (u16*)(ws + 12 * MB);
    u16* Wob = (u16*)(ws + 14 * MB);
    u16* Qb  = (u16*)(ws + 16 * MB);
    u16* Kb  = (u16*)(ws + 24 * MB);
    u16* Vb  = (u16*)(ws + 32 * MB);
    u16* Yb  = (u16*)(ws + 40 * MB);

    cast_all<<<8192, 256, 0, stream>>>(x, Wq, Wk, Wv, Wo, xb, Wqb, Wkb, Wvb, Wob);
    qkv_gemm<<<dim3(DM / 128, BB * SS / 128, 3), 256, 0, stream>>>(
        xb, Wqb, Wkb, Wvb, tp, cosp, sinp, use_rope, Qb, Kb, Vb);
    attn_kernel<<<dim3(BB * NH, 16), 512, 0, stream>>>(Qb, Kb, Vb, Yb);
    out_gemm<<<dim3(DM / 64, BB * SS / 128), 256, 0, stream>>>(Yb, Wob, out);
}

// Round 9
// 181.332 us; speedup vs baseline: 1.2674x; 1.0324x over previous
//
#include <hip/hip_runtime.h>
#include <math.h>

#define BB 2
#define SS 2048
#define DM 1024
#define NH 16
#define HD 64

typedef __attribute__((ext_vector_type(8))) __bf16 bf16x8;
typedef __attribute__((ext_vector_type(4))) __bf16 bf16x4;
typedef __attribute__((ext_vector_type(8))) unsigned short u16x8;
typedef __attribute__((ext_vector_type(4))) float f32x4;
typedef unsigned short u16;
typedef unsigned int u32;
typedef __attribute__((address_space(1))) unsigned int u32g;
typedef __attribute__((address_space(3))) unsigned int u32l;

#define CEXP 0.18033688011112042f   // 0.125 * log2(e)

static __device__ __forceinline__ u16 f2bf(float f) {
    __bf16 h = (__bf16)f;
    return __builtin_bit_cast(unsigned short, h);
}

// async global->LDS, 16B/lane; lds base wave-uniform, lane i lands at base + i*16B
static __device__ __forceinline__ void gld16(const u16* g, u16* l) {
    __builtin_amdgcn_global_load_lds((const u32g*)g, (u32l*)l, 16, 0, 0);
}

// ---------------- fused fp32 -> bf16 cast for x + 4 weights ----------------
__global__ __launch_bounds__(256)
void cast_all(const float* __restrict__ x,
              const float* __restrict__ wq, const float* __restrict__ wk,
              const float* __restrict__ wv, const float* __restrict__ wo,
              u16* __restrict__ xb, u16* __restrict__ wqb, u16* __restrict__ wkb,
              u16* __restrict__ wvb, u16* __restrict__ wob)
{
    const int N4X = (BB * SS * DM) / 4;   // 1048576
    const int N4W = (DM * DM) / 4;        // 262144
    int i = blockIdx.x * 256 + threadIdx.x;
    const float* src; u16* dst; int off;
    if (i < N4X) { src = x; dst = xb; off = i; }
    else {
        int i2 = i - N4X;
        int w = i2 >> 18;
        off = i2 & (N4W - 1);
        switch (w) {
            case 0:  src = wq; dst = wqb; break;
            case 1:  src = wk; dst = wkb; break;
            case 2:  src = wv; dst = wvb; break;
            default: src = wo; dst = wob; break;
        }
    }
    float4 v = ((const float4*)src)[off];
    ushort4 o;
    o.x = f2bf(v.x); o.y = f2bf(v.y); o.z = f2bf(v.z); o.w = f2bf(v.w);
    ((ushort4*)dst)[off] = o;
}

// ---------------- QKV projection: BK=64 swizzled gld16; fp32 RoPE; transposed epilogue ------
// z==0/1 -> Q/K in [b,h,s,d]; z==2 -> V written TRANSPOSED [b,h,d,s] for attn gld16 staging.
__global__ __launch_bounds__(256, 3)
void qkv_gemm(const u16* __restrict__ X,
              const u16* __restrict__ Wq, const u16* __restrict__ Wk,
              const u16* __restrict__ Wv,
              const int* __restrict__ tp, const float* __restrict__ cosp,
              const float* __restrict__ sinp, const int* __restrict__ use_rope,
              u16* __restrict__ Q, u16* __restrict__ K, u16* __restrict__ V)
{
    const u16* W; u16* dst;
    if (blockIdx.z == 0)      { W = Wq; dst = Q; }
    else if (blockIdx.z == 1) { W = Wk; dst = K; }
    else                      { W = Wv; dst = V; }

    __shared__ u16 SH[4 * 64 * 68];   // 34816 B: {As,Bs} during k-loop; Ts after
    u16* As = SH;                     // 128 x 64
    u16* Bs = SH + 8192;              // 128 x 64
    const int t  = threadIdx.x;
    const int wv = t >> 6, L = t & 63, ln = L & 15, qd = L >> 4;
    const int i0 = blockIdx.y * 128, j0 = blockIdx.x * 128;
    const int wm = (wv >> 1) * 64, wn = (wv & 1) * 64;
    const int srow = L >> 3;
    const int scg  = ((L & 7) ^ (L >> 3)) * 8;

    f32x4 acc[4][4];
    #pragma unroll
    for (int a = 0; a < 4; ++a)
        #pragma unroll
        for (int b = 0; b < 4; ++b)
            #pragma unroll
            for (int e = 0; e < 4; ++e) acc[a][b][e] = 0.f;

    for (int k0 = 0; k0 < DM; k0 += 64) {
        __syncthreads();
        #pragma unroll
        for (int g = 0; g < 4; ++g) {
            int rb = wv * 32 + g * 8;
            gld16(X + (size_t)(i0 + rb + srow) * DM + k0 + scg, &As[rb * 64]);
            gld16(W + (size_t)(j0 + rb + srow) * DM + k0 + scg, &Bs[rb * 64]);
        }
        __syncthreads();
        bf16x8 a[4][2], b[4][2];
        #pragma unroll
        for (int mi = 0; mi < 4; ++mi)
            #pragma unroll
            for (int kd = 0; kd < 2; ++kd)
                a[mi][kd] = *(const bf16x8*)&As[(wm + mi * 16 + ln) * 64 + (((kd * 4 + qd) ^ (ln & 7)) * 8)];
        #pragma unroll
        for (int ni = 0; ni < 4; ++ni)
            #pragma unroll
            for (int kd = 0; kd < 2; ++kd)
                b[ni][kd] = *(const bf16x8*)&Bs[(wn + ni * 16 + ln) * 64 + (((kd * 4 + qd) ^ (ln & 7)) * 8)];
        #pragma unroll
        for (int kd = 0; kd < 2; ++kd)
            #pragma unroll
            for (int mi = 0; mi < 4; ++mi)
                #pragma unroll
                for (int ni = 0; ni < 4; ++ni)
                    acc[mi][ni] = __builtin_amdgcn_mfma_f32_16x16x32_bf16(a[mi][kd], b[ni][kd], acc[mi][ni], 0, 0, 0);
    }

    // ---- RoPE in fp32 on accumulators (lane pairs hold adjacent d) ----
    const int rope_on = (blockIdx.z < 2) ? use_rope[0] : 0;
    if (rope_on) {
        #pragma unroll
        for (int mi = 0; mi < 4; ++mi)
            #pragma unroll
            for (int r = 0; r < 4; ++r) {
                int gi = i0 + wm + mi * 16 + qd * 4 + r;
                int s = gi & 2047;
                int pos = tp[s];
                #pragma unroll
                for (int ni = 0; ni < 4; ++ni) {
                    int d = wn + ni * 16 + ln;
                    int dh = d & 63;
                    float c  = cosp[pos * 32 + (dh >> 1)];
                    float sn = sinp[pos * 32 + (dh >> 1)];
                    float v = acc[mi][ni][r];
                    float pv = __shfl_xor(v, 1);
                    acc[mi][ni][r] = (dh & 1) ? (v * c + pv * sn) : (v * c - pv * sn);
                }
            }
    }

    // ---- epilogue: per-wave LDS transpose ----
    __syncthreads();
    u16* Ts = SH + wv * (64 * 68);    // 64 rows (s) x 64 cols (d), stride 68
    #pragma unroll
    for (int mi = 0; mi < 4; ++mi)
        #pragma unroll
        for (int ni = 0; ni < 4; ++ni)
            #pragma unroll
            for (int r = 0; r < 4; ++r)
                Ts[(mi * 16 + qd * 4 + r) * 68 + ni * 16 + ln] = f2bf(acc[mi][ni][r]);

    const int h  = blockIdx.x * 2 + (wv & 1);
    const int sb = i0 + wm;
    const int b_ = sb >> 11, s0 = sb & 2047;
    if (blockIdx.z < 2) {
        // Q/K: [b,h,s,d] coalesced u16x8 rows
        const int lrow = L >> 3, lcol = (L & 7) * 8;
        #pragma unroll
        for (int r2 = 0; r2 < 8; ++r2) {
            int row = lrow + r2 * 8;
            u16x8 val = *(const u16x8*)&Ts[row * 68 + lcol];
            *(u16x8*)&dst[(((size_t)(b_ * NH + h)) * SS + s0 + row) * HD + lcol] = val;
        }
    } else {
        // V: transposed [b,h,d,s] (8 s per lane along the row)
        const int sch = (L & 7) * 8;      // s-chunk within the 64-row tile
        const int dr0 = L >> 3;           // d-row base
        #pragma unroll
        for (int r2 = 0; r2 < 8; ++r2) {
            int d = dr0 + r2 * 8;
            u16x8 val;
            #pragma unroll
            for (int u = 0; u < 8; ++u) val[u] = Ts[(sch + u) * 68 + d];
            *(u16x8*)&dst[(((size_t)(b_ * NH + h)) * HD + d) * SS + s0 + sch] = val;
        }
    }
}

// ---------------- output projection, 128x64 tile, fp32 transposed epilogue ----------------
__global__ __launch_bounds__(256, 2)
void out_gemm(const u16* __restrict__ X, const u16* __restrict__ W,
              float* __restrict__ dst)
{
    __shared__ char SHB[36864];       // {As 16K, Bs 8K} k-loop; Ts 36K epilogue
    u16* As = (u16*)SHB;              // 128 x 64
    u16* Bs = (u16*)SHB + 8192;       // 64 x 64
    const int t  = threadIdx.x;
    const int wv = t >> 6, L = t & 63, ln = L & 15, qd = L >> 4;
    const int i0 = blockIdx.y * 128, j0 = blockIdx.x * 64;
    const int wm = (wv >> 1) * 64, wn = (wv & 1) * 32;
    const int srow = L >> 3;
    const int scg  = ((L & 7) ^ (L >> 3)) * 8;

    f32x4 acc[4][2];
    #pragma unroll
    for (int mi = 0; mi < 4; ++mi)
        #pragma unroll
        for (int ni = 0; ni < 2; ++ni)
            #pragma unroll
            for (int e = 0; e < 4; ++e) acc[mi][ni][e] = 0.f;

    for (int k0 = 0; k0 < DM; k0 += 64) {
        __syncthreads();
        #pragma unroll
        for (int g = 0; g < 4; ++g) {
            int rb = wv * 32 + g * 8;
            gld16(X + (size_t)(i0 + rb + srow) * DM + k0 + scg, &As[rb * 64]);
        }
        #pragma unroll
        for (int g = 0; g < 2; ++g) {
            int rb = wv * 16 + g * 8;
            gld16(W + (size_t)(j0 + rb + srow) * DM + k0 + scg, &Bs[rb * 64]);
        }
        __syncthreads();
        bf16x8 a[4][2], b[2][2];
        #pragma unroll
        for (int mi = 0; mi < 4; ++mi)
            #pragma unroll
            for (int kd = 0; kd < 2; ++kd)
                a[mi][kd] = *(const bf16x8*)&As[(wm + mi * 16 + ln) * 64 + (((kd * 4 + qd) ^ (ln & 7)) * 8)];
        #pragma unroll
        for (int ni = 0; ni < 2; ++ni)
            #pragma unroll
            for (int kd = 0; kd < 2; ++kd)
                b[ni][kd] = *(const bf16x8*)&Bs[(wn + ni * 16 + ln) * 64 + (((kd * 4 + qd) ^ (ln & 7)) * 8)];
        #pragma unroll
        for (int kd = 0; kd < 2; ++kd)
            #pragma unroll
            for (int mi = 0; mi < 4; ++mi)
                #pragma unroll
                for (int ni = 0; ni < 2; ++ni)
                    acc[mi][ni] = __builtin_amdgcn_mfma_f32_16x16x32_bf16(a[mi][kd], b[ni][kd], acc[mi][ni], 0, 0, 0);
    }

    __syncthreads();
    float* Ts = (float*)SHB + wv * (64 * 36);   // 64 rows x 32 cols, stride 36
    #pragma unroll
    for (int mi = 0; mi < 4; ++mi)
        #pragma unroll
        for (int ni = 0; ni < 2; ++ni)
            #pragma unroll
            for (int r = 0; r < 4; ++r)
                Ts[(mi * 16 + qd * 4 + r) * 36 + ni * 16 + ln] = acc[mi][ni][r];

    const int lrow = L >> 3, lch = L & 7;
    #pragma unroll
    for (int r2 = 0; r2 < 8; ++r2) {
        int row = lrow + r2 * 8;
        float4 v = *(const float4*)&Ts[row * 36 + lch * 4];
        *(float4*)&dst[(size_t)(i0 + wm + row) * DM + j0 + wn + lch * 4] = v;
    }
}

// ---------------- MFMA flash attention: wave-specialized, O^T accumulation, gld16 K & V^T ----
// Waves 0-3 = q-tile p, waves 4-7 = q-tile 31-p. S^T = mfma(K,Q) puts q in lane;
// O^T = mfma(V^T, P) keeps q in lane -> alpha/l fully in-lane (no shuffles).
static __device__ __forceinline__ void group_step(
    const u16* KsB, const bf16x8 qf[2], u16* psw,
    bool diag, int rowg, int j0, int ln, int qd,
    float& m, float& l, f32x4* o, bf16x8& pf0, bf16x8& pf1)
{
    const int pm = 2 * (ln & 7);     // even XOR mask over 8B granules
    f32x4 s[4];
    #pragma unroll
    for (int mt = 0; mt < 4; ++mt) {
        bf16x8 a0 = *(const bf16x8*)&KsB[(mt * 16 + ln) * 64 + ((qd ^ (ln & 7)) * 8)];
        bf16x8 a1 = *(const bf16x8*)&KsB[(mt * 16 + ln) * 64 + (((4 + qd) ^ (ln & 7)) * 8)];
        #pragma unroll
        for (int e = 0; e < 4; ++e) s[mt][e] = 0.f;
        s[mt] = __builtin_amdgcn_mfma_f32_16x16x32_bf16(a0, qf[0], s[mt], 0, 0, 0);
        s[mt] = __builtin_amdgcn_mfma_f32_16x16x32_bf16(a1, qf[1], s[mt], 0, 0, 0);
    }
    if (diag) {
        #pragma unroll
        for (int mt = 0; mt < 4; ++mt)
            #pragma unroll
            for (int r = 0; r < 4; ++r)
                if (j0 + mt * 16 + qd * 4 + r > rowg) s[mt][r] = -3.0e38f;
    }
    float rm = s[0][0];
    #pragma unroll
    for (int mt = 0; mt < 4; ++mt)
        #pragma unroll
        for (int r = 0; r < 4; ++r) rm = fmaxf(rm, s[mt][r]);
    rm = fmaxf(rm, __shfl_xor(rm, 16));
    rm = fmaxf(rm, __shfl_xor(rm, 32));
    float nm = fmaxf(m, rm);
    float alpha = exp2f((m - nm) * CEXP);
    float nmc = nm * CEXP;
    float rs = 0.f;
    #pragma unroll
    for (int mt = 0; mt < 4; ++mt) {
        bf16x4 pk;
        #pragma unroll
        for (int r = 0; r < 4; ++r) {
            float pv = exp2f(fmaf(s[mt][r], CEXP, -nmc));
            rs += pv;
            pk[r] = (__bf16)pv;
        }
        *(bf16x4*)(psw + ln * 64 + ((mt * 4 + qd) ^ pm) * 4) = pk;
    }
    rs += __shfl_xor(rs, 16);
    rs += __shfl_xor(rs, 32);
    l = l * alpha + rs;
    m = nm;
    // O^T layout: col = q = own lane -> in-lane rescale, no broadcast
    #pragma unroll
    for (int ni = 0; ni < 4; ++ni)
        #pragma unroll
        for (int r = 0; r < 4; ++r) o[ni][r] *= alpha;
    pf0 = *(const bf16x8*)(psw + ln * 64 + ((qd * 2) ^ pm) * 4);
    pf1 = *(const bf16x8*)(psw + ln * 64 + ((8 + qd * 2) ^ pm) * 4);
}

__global__ __launch_bounds__(512, 4)
void attn_kernel(const u16* __restrict__ Q, const u16* __restrict__ K,
                 const u16* __restrict__ V, u16* __restrict__ Y)
{
    __shared__ u16 Ks[2][64 * 64];     // [key][d], gld16 source-swizzled, double-buffered
    __shared__ u16 Vt[2][64 * 64];     // [d][key] from global V^T, gld16, double-buffered
    __shared__ u16 Ps[8][16 * 64];     // per-wave P round-trip, granule-swizzled

    const int t  = threadIdx.x;
    const int wv = t >> 6, L = t & 63, ln = L & 15, qd = L >> 4;
    const int wsub = wv & 3, grp = wv >> 2;
    const int bh = blockIdx.x, p = blockIdx.y;
    const int qb = (grp ? (31 - p) : p) * 64;
    const u16* Qp = Q + (size_t)bh * SS * HD;
    const u16* Kp = K + (size_t)bh * SS * HD;
    const u16* Vp = V + (size_t)bh * HD * SS;   // transposed [d][s]
    const int srow = L >> 3;
    const int scg  = ((L & 7) ^ (L >> 3)) * 8;

    const int ntile   = 32 - p;
    const int myTiles = grp ? ntile : (p + 1);

    bf16x8 qf[2];
    {
        const u16* rq = Qp + (size_t)(qb + wsub * 16 + ln) * HD;
        qf[0] = *(const bf16x8*)(rq + qd * 8);
        qf[1] = *(const bf16x8*)(rq + 32 + qd * 8);
    }

    f32x4 o[4];
    #pragma unroll
    for (int ni = 0; ni < 4; ++ni)
        #pragma unroll
        for (int e = 0; e < 4; ++e) o[ni][e] = 0.f;
    float m = -3.0e38f, l = 0.f;

    // ---- prologue: stage tile 0 (K: 8 waves x 8 rows; V^T: 8 waves x 8 d-rows) ----
    gld16(Kp + (size_t)(wv * 8 + srow) * HD + scg, &Ks[0][(wv * 8) * 64]);
    gld16(Vp + (size_t)(wv * 8 + srow) * SS + scg, &Vt[0][(wv * 8) * 64]);
    __syncthreads();

    for (int tix = 0; tix < ntile; ++tix) {
        const int j0 = tix * 64;
        const int buf = tix & 1;
        const bool more = (tix + 1 < ntile);

        // ---- prefetch tile t+1 async into buf^1 ----
        if (more) {
            const int j1 = j0 + 64;
            gld16(Kp + (size_t)(j1 + wv * 8 + srow) * HD + scg, &Ks[buf ^ 1][(wv * 8) * 64]);
            gld16(Vp + (size_t)(wv * 8 + srow) * SS + j1 + scg, &Vt[buf ^ 1][(wv * 8) * 64]);
        }

        if (tix < myTiles) {
            bf16x8 pf0, pf1;
            group_step(Ks[buf], qf, &Ps[wv][0], tix == myTiles - 1,
                       qb + wsub * 16 + ln, j0, ln, qd, m, l, o, pf0, pf1);
            #pragma unroll
            for (int kc = 0; kc < 2; ++kc)
                #pragma unroll
                for (int ni = 0; ni < 4; ++ni) {
                    bf16x8 vf = *(const bf16x8*)&Vt[buf][(ni * 16 + ln) * 64 + (((kc * 4 + qd) ^ (ln & 7)) * 8)];
                    // O^T = V^T * P : A = V^T frag, B = P frag
                    o[ni] = __builtin_amdgcn_mfma_f32_16x16x32_bf16(vf, kc ? pf1 : pf0, o[ni], 0, 0, 0);
                }
        }
        __syncthreads();
    }

    // ---- epilogue: normalize in-lane, write Y bf16 (b, s, d_model), 8B runs ----
    const int b = bh >> 4, h = bh & 15;
    const float inv = 1.f / l;
    const int sq = qb + wsub * 16 + ln;
    #pragma unroll
    for (int ni = 0; ni < 4; ++ni) {
        bf16x4 pk;
        #pragma unroll
        for (int r = 0; r < 4; ++r) pk[r] = (__bf16)(o[ni][r] * inv);
        *(bf16x4*)&Y[((size_t)(b * SS + sq)) * DM + h * HD + ni * 16 + qd * 4] = pk;
    }
}

extern "C" void kernel_launch(void* const* d_in, const int* in_sizes, int n_in,
                              void* d_out, int out_size, void* d_ws, size_t ws_size,
                              hipStream_t stream)
{
    const float* x        = (const float*)d_in[0];
    const int*   tp       = (const int*)d_in[1];
    const int*   use_rope = (const int*)d_in[2];
    const float* Wq       = (const float*)d_in[3];
    const float* Wk       = (const float*)d_in[4];
    const float* Wv       = (const float*)d_in[5];
    const float* Wo       = (const float*)d_in[6];
    const float* cosp     = (const float*)d_in[7];
    const float* sinp     = (const float*)d_in[8];
    float* out = (float*)d_out;

    char* ws = (char*)d_ws;
    const size_t MB = 1 << 20;
    u16* xb  = (u16*)(ws);
    u16* Wqb = (u16*)(ws + 8 * MB);
    u16* Wkb = (u16*)(ws + 10 * MB);
    u16* Wvb = (u16*)(ws + 12 * MB);
    u16* Wob = (u16*)(ws + 14 * MB);
    u16* Qb  = (u16*)(ws + 16 * MB);
    u16* Kb  = (u16*)(ws + 24 * MB);
    u16* Vb  = (u16*)(ws + 32 * MB);
    u16* Yb  = (u16*)(ws + 40 * MB);

    cast_all<<<8192, 256, 0, stream>>>(x, Wq, Wk, Wv, Wo, xb, Wqb, Wkb, Wvb, Wob);
    qkv_gemm<<<dim3(DM / 128, BB * SS / 128, 3), 256, 0, stream>>>(
        xb, Wqb, Wkb, Wvb, tp, cosp, sinp, use_rope, Qb, Kb, Vb);
    attn_kernel<<<dim3(BB * NH, 16), 512, 0, stream>>>(Qb, Kb, Vb, Yb);
    out_gemm<<<dim3(DM / 64, BB * SS / 128), 256, 0, stream>>>(Yb, Wob, out);
}